// Round 5
// 540.223 us; speedup vs baseline: 1.0258x; 1.0258x over previous
//
#include <hip/hip_runtime.h>
#include <hip/hip_bf16.h>

// Problem constants
#define EDIM 1024
#define HHEADS 16
#define DHEAD 64
#define BB 4
#define NSEQ 4096
#define NTOK 16384   // BB*NSEQ
#define KVSPLIT 16

typedef unsigned short u16;
using frag8 = __attribute__((ext_vector_type(8))) short;   // 8 bf16 (4 VGPRs)
using facc4 = __attribute__((ext_vector_type(4))) float;   // 4 f32 acc

__device__ __forceinline__ float b2f(u16 u) {
  union { unsigned int i; float f; } c; c.i = ((unsigned int)u) << 16; return c.f;
}
__device__ __forceinline__ u16 f2b(float f) {
  __hip_bfloat16 h = __float2bfloat16(f);   // RNE
  union { __hip_bfloat16 h; u16 u; } c; c.h = h; return c.u;
}
__device__ __forceinline__ void gl2lds16(const void* g, void* l) {
  __builtin_amdgcn_global_load_lds(
      (const __attribute__((address_space(1))) unsigned int*)g,
      (__attribute__((address_space(3))) unsigned int*)l, 16, 0, 0);
}

// ---------------------------------------------------------------------------
// Dtype probe: flag[0]=1 -> inputs are bf16, 0 -> f32 (per reference).
// ---------------------------------------------------------------------------
__global__ void detect_dtype(const u16* __restrict__ src, unsigned* __restrict__ flag) {
  const int lane = threadIdx.x;                    // 64 threads
  const unsigned u = src[(size_t)lane * 200000];   // even u16 indices
  const unsigned e = (u >> 7) & 0xFF;
  const bool inl = (u == 0) || (e >= 100 && e <= 135);
  const unsigned long long m = __ballot(inl);
  if (lane == 0) flag[0] = (__popcll(m) >= 32) ? 1u : 0u;
}

// f32 -> bf16 conversion; NO-OP in bf16 world (GEMM reads raw ptr directly).
__global__ __launch_bounds__(256) void cvt_bf16(
    const void* __restrict__ src, u16* __restrict__ dst, int n,
    const unsigned* __restrict__ flag) {
  if (flag[0] == 1) return;
  const int i0 = (blockIdx.x * 256 + threadIdx.x) * 8;
  if (i0 >= n) return;
  const float4 a = ((const float4*)src)[i0 >> 2];
  const float4 b = ((const float4*)src)[(i0 >> 2) + 1];
  ushort4 lo, hi;
  lo.x = f2b(a.x); lo.y = f2b(a.y); lo.z = f2b(a.z); lo.w = f2b(a.w);
  hi.x = f2b(b.x); hi.y = f2b(b.y); hi.z = f2b(b.z); hi.w = f2b(b.w);
  ((ushort4*)dst)[i0 >> 2] = lo;
  ((ushort4*)dst)[(i0 >> 2) + 1] = hi;
}

// Convert 8 vectors of 1024 elements each (biases, gains, betas). Always runs.
struct Ptr8 { const void* s[8]; u16* d[8]; };
__global__ __launch_bounds__(256) void cvt8(Ptr8 p, const unsigned* __restrict__ flag) {
  const int t = blockIdx.x * 256 + threadIdx.x;    // 0..1023
  const int v = t >> 7;
  const int i0 = (t & 127) * 8;
  const void* s = p.s[v];
  u16* d = p.d[v];
  ushort4 lo, hi;
  if (flag[0] == 0) {
    const float4 a = ((const float4*)s)[i0 >> 2];
    const float4 b = ((const float4*)s)[(i0 >> 2) + 1];
    lo.x = f2b(a.x); lo.y = f2b(a.y); lo.z = f2b(a.z); lo.w = f2b(a.w);
    hi.x = f2b(b.x); hi.y = f2b(b.y); hi.z = f2b(b.z); hi.w = f2b(b.w);
  } else {
    lo = ((const ushort4*)s)[i0 >> 2];
    hi = ((const ushort4*)s)[(i0 >> 2) + 1];
  }
  ((ushort4*)d)[i0 >> 2] = lo;
  ((ushort4*)d)[(i0 >> 2) + 1] = hi;
}

// ---------------------------------------------------------------------------
// GEMM: C[M,1024] = A[M,1024] @ W[1024,1024]^T + bias (bf16 in, f32 acc).
// 256x256 tile, BK=64, 512 threads (8 waves, 2Mx4N), 8-phase counted-vmcnt
// schedule (T2 swizzle + T3/T4 + T5, per the m201 template).
//
// LDS: As/Bs[2 buf][2 region][128][64] bf16 = 128 KiB. Region qm of A = the
// rows read by qm-phases = global rows {wm*128+qm*64 .. +64} for wm=0,1.
// Region qn of B analogous (4 chunks of 32 W-rows). global_load_lds writes
// linearly; the XOR bank swizzle (colgroup ^= row&7, 16B granules) is applied
// by pre-swizzling the per-lane GLOBAL source column and reading ds with the
// same XOR (m173/m201 both-sides pattern).
//
// Schedule per iteration (tiles T=2i in buf0 phases 1-4, T+1 in buf1 phases
// 5-8; quadrant order q(0,0),q(0,1),q(1,0),q(1,1) per tile):
//   ph1: issue buf1.{A1,B1}(T+1)   ph3: issue buf0.A0(T+2)
//   ph4: issue buf0.B0(T+2), vmcnt(4)
//   ph5: issue buf0.{A1,B1}(T+2)   ph7: issue buf1.A0(T+3)
//   ph8: issue buf1.B0(T+3), vmcnt(4)
// Every issue is after the end-barrier following the region's last read of
// the outgoing tile (and those readers drained their ds_reads via lgkmcnt(0)
// before that barrier); every first read is after a vmcnt that retires the
// staging loads (ledger verified phase-by-phase). Final pair drains vmcnt(0).
// ---------------------------------------------------------------------------
#define STA(BUF, QM, T)                                                       \
  gl2lds16(Ag + (size_t)(QM) * 64 * EDIM + (size_t)(T) * 64,                  \
           AsW + (BUF) * 16384 + (QM) * 8192);                                \
  gl2lds16(Ag + (size_t)(QM) * 64 * EDIM + 128 * EDIM + (size_t)(T) * 64,     \
           AsW + (BUF) * 16384 + (QM) * 8192 + 4096);

#define STB(BUF, QN, T)                                                       \
  gl2lds16(Bg + (size_t)(QN) * 32 * EDIM + (size_t)(T) * 64,                  \
           BsW + (BUF) * 16384 + (QN) * 8192);                                \
  gl2lds16(Bg + (size_t)(QN) * 32 * EDIM + 128 * EDIM + (size_t)(T) * 64,     \
           BsW + (BUF) * 16384 + (QN) * 8192 + 4096);

#define VM(N) asm volatile("s_waitcnt vmcnt(" #N ")" ::: "memory");

#define PH(BUF, QM, QN, ISSUE, TAIL)                                          \
  {                                                                           \
    frag8 af[4][2], bq[2][2];                                                 \
    _Pragma("unroll") for (int i = 0; i < 4; ++i) {                           \
      const u16* rp = &As[BUF][QM][wm * 64 + i * 16 + fr][0];                 \
      af[i][0] = *(const frag8*)(rp + c0);                                    \
      af[i][1] = *(const frag8*)(rp + c1);                                    \
    }                                                                         \
    _Pragma("unroll") for (int j = 0; j < 2; ++j) {                           \
      const u16* rp = &Bs[BUF][QN][wn * 32 + j * 16 + fr][0];                 \
      bq[j][0] = *(const frag8*)(rp + c0);                                    \
      bq[j][1] = *(const frag8*)(rp + c1);                                    \
    }                                                                         \
    ISSUE                                                                     \
    __builtin_amdgcn_s_barrier();                                             \
    asm volatile("s_waitcnt lgkmcnt(0)" ::: "memory");                        \
    __builtin_amdgcn_sched_barrier(0);                                        \
    __builtin_amdgcn_s_setprio(1);                                            \
    _Pragma("unroll") for (int kk = 0; kk < 2; ++kk)                          \
      _Pragma("unroll") for (int i = 0; i < 4; ++i)                           \
        _Pragma("unroll") for (int j = 0; j < 2; ++j)                         \
          acc[(QM) * 4 + i][(QN) * 2 + j] =                                   \
              __builtin_amdgcn_mfma_f32_16x16x32_bf16(                        \
                  af[i][kk], bq[j][kk], acc[(QM) * 4 + i][(QN) * 2 + j],      \
                  0, 0, 0);                                                   \
    __builtin_amdgcn_s_setprio(0);                                            \
    TAIL                                                                      \
    __builtin_amdgcn_s_barrier();                                             \
    __builtin_amdgcn_sched_barrier(0);                                        \
  }

__global__ __launch_bounds__(512, 2) void gemm256(
    const void* __restrict__ Araw, const u16* __restrict__ Acvt,
    const void* __restrict__ Wraw, const u16* __restrict__ Wcvt,
    const u16* __restrict__ bias, u16* __restrict__ C,
    const unsigned* __restrict__ flag, int outMode)
{
  __shared__ __align__(16) u16 As[2][2][128][64];   // 64 KiB
  __shared__ __align__(16) u16 Bs[2][2][128][64];   // 64 KiB

  const int tid  = threadIdx.x;
  const int lane = tid & 63;
  const int w    = tid >> 6;       // 0..7
  const int wm   = w >> 2;         // 0..1 (M half)
  const int wn   = w & 3;          // 0..3 (N quarter)

  // XCD-bijective swizzle (256 blocks, 256%8==0): each XCD gets 8 m-panels x
  // all 4 n-panels -> A panels L2-shared within an XCD.
  const int bid0 = blockIdx.x;
  const int bid  = (bid0 & 7) * 32 + (bid0 >> 3);
  const int rowBase = (bid >> 2) * 256;
  const int colBase = (bid & 3) * 256;

  const bool bfw = (flag[0] == 1);
  const u16* A  = bfw ? (const u16*)Araw : Acvt;
  const u16* Wt = bfw ? (const u16*)Wraw : Wcvt;

  // Staging addressing: one gl2lds = 8 waves x 64 lanes x 16B = 64 rows x 64
  // cols. Wave w covers rows [w*8, w*8+8); lane's 16B slot = colgroup lane&7,
  // pre-swizzled source colgroup = (lane&7) ^ (row&7) = (lane&7) ^ (lane>>3).
  const int lr = w * 8 + (lane >> 3);               // row within 64-row op
  const int sc = 8 * ((lane & 7) ^ (lane >> 3));    // swizzled col (elems)
  const u16* Ag = A  + (size_t)(rowBase + lr) * EDIM + sc;
  const u16* Bg = Wt + (size_t)(colBase + (lr >> 5) * 64 + (lr & 31)) * EDIM + sc;
  u16* AsW = &As[0][0][w * 8][0];   // + buf*16384 + region*8192 + o*4096
  u16* BsW = &Bs[0][0][w * 8][0];

  // ds_read fragment addressing (16x16x32 A/B layout: row fr, k = qd*8+kk*32)
  const int fr = lane & 15;
  const int qd = lane >> 4;
  const int sw = fr & 7;
  const int c0 = 8 * (qd ^ sw);          // kk=0 swizzled col offset (elems)
  const int c1 = 8 * ((qd + 4) ^ sw);    // kk=1

  facc4 acc[8][4];
#pragma unroll
  for (int i = 0; i < 8; ++i)
#pragma unroll
    for (int j = 0; j < 4; ++j) acc[i][j] = (facc4){0.f, 0.f, 0.f, 0.f};

  // Prologue: tile0 fully (8 ops), tile1 A0+B0 (4 ops); retire tile0.
  STA(0, 0, 0) STB(0, 0, 0) STA(0, 1, 0) STB(0, 1, 0)
  STA(1, 0, 1) STB(1, 0, 1)
  VM(4)
  __builtin_amdgcn_s_barrier();
  __builtin_amdgcn_sched_barrier(0);

#pragma unroll 1
  for (int it = 0; it < 7; ++it) {                  // tiles 0..13
    const int t1 = 2 * it + 1, t2 = t1 + 1, t3 = t1 + 2;
    PH(0, 0, 0, STA(1, 1, t1) STB(1, 1, t1), )
    PH(0, 0, 1, , )
    PH(0, 1, 0, STA(0, 0, t2), )
    PH(0, 1, 1, STB(0, 0, t2), VM(4))
    PH(1, 0, 0, STA(0, 1, t2) STB(0, 1, t2), )
    PH(1, 0, 1, , )
    PH(1, 1, 0, STA(1, 0, t3), )
    PH(1, 1, 1, STB(1, 0, t3), VM(4))
  }
  // Final pair: tiles 14 (buf0), 15 (buf1); drain at phase 4.
  PH(0, 0, 0, STA(1, 1, 15) STB(1, 1, 15), )
  PH(0, 0, 1, , )
  PH(0, 1, 0, , )
  PH(0, 1, 1, , VM(0))
  PH(1, 0, 0, , )
  PH(1, 0, 1, , )
  PH(1, 1, 0, , )
  PH(1, 1, 1, , )

  // Epilogue: bias + store (C/D layout: col=lane&15, row=quad*4+reg).
  const bool f32out = (outMode == 1) && !bfw;
  float* Cf = (float*)C;
  float bvv[4];
#pragma unroll
  for (int j = 0; j < 4; ++j)
    bvv[j] = b2f(bias[colBase + wn * 64 + j * 16 + fr]);
#pragma unroll
  for (int i = 0; i < 8; ++i) {
#pragma unroll
    for (int r = 0; r < 4; ++r) {
      const int row = rowBase + wm * 128 + i * 16 + qd * 4 + r;
      const size_t ro = (size_t)row * EDIM + colBase + wn * 64 + fr;
#pragma unroll
      for (int j = 0; j < 4; ++j) {
        const float val = acc[i][j][r] + bvv[j];
        if (f32out) Cf[ro + j * 16] = val;
        else        C[ro + j * 16]  = f2b(val);
      }
    }
  }
}

// ---------------------------------------------------------------------------
// LayerNorm (+g,beta) then elu+1, per row of 1024 (bf16 in/out, in-place OK).
// ---------------------------------------------------------------------------
__global__ __launch_bounds__(256) void ln_elu(
    const u16* __restrict__ X, const u16* __restrict__ g,
    const u16* __restrict__ beta, u16* __restrict__ Y)
{
  __shared__ float wsum[4], wsq[4];
  const int row = blockIdx.x, tid = threadIdx.x;
  const ushort4 xu = ((const ushort4*)(X + (size_t)row * EDIM))[tid];
  float x[4] = { b2f(xu.x), b2f(xu.y), b2f(xu.z), b2f(xu.w) };
  float s  = x[0] + x[1] + x[2] + x[3];
  float ss = x[0]*x[0] + x[1]*x[1] + x[2]*x[2] + x[3]*x[3];
#pragma unroll
  for (int off = 32; off > 0; off >>= 1) {
    s  += __shfl_down(s,  off, 64);
    ss += __shfl_down(ss, off, 64);
  }
  if ((tid & 63) == 0) { wsum[tid >> 6] = s; wsq[tid >> 6] = ss; }
  __syncthreads();
  const float S  = wsum[0] + wsum[1] + wsum[2] + wsum[3];
  const float SS = wsq[0] + wsq[1] + wsq[2] + wsq[3];
  const float mu  = S * (1.0f / EDIM);
  const float var = SS * (1.0f / EDIM) - mu * mu;
  const float rs  = rsqrtf(var + 1e-5f);
  const ushort4 gu = ((const ushort4*)g)[tid];
  const ushort4 bu = ((const ushort4*)beta)[tid];
  float gg[4] = { b2f(gu.x), b2f(gu.y), b2f(gu.z), b2f(gu.w) };
  float bb[4] = { b2f(bu.x), b2f(bu.y), b2f(bu.z), b2f(bu.w) };
  ushort4 out;
  u16 o[4];
#pragma unroll
  for (int c = 0; c < 4; ++c) {
    float y = (x[c] - mu) * rs * gg[c] + bb[c];
    y = (y > 0.f) ? (y + 1.f) : __expf(y);   // elu(y)+1
    o[c] = f2b(y);
  }
  out.x = o[0]; out.y = o[1]; out.z = o[2]; out.w = o[3];
  ((ushort4*)(Y + (size_t)row * EDIM))[tid] = out;
}

// ---------------------------------------------------------------------------
// Stage 1: per-(split,h,b) partial kv_sum (64x64 f32) + partial k_sum -> own
// global slots (NO atomics). 256 n per block, 2 chunks of 128.
// ---------------------------------------------------------------------------
__global__ __launch_bounds__(256) void kv_partial(
    const u16* __restrict__ Km, const u16* __restrict__ V,
    float* __restrict__ partials, float* __restrict__ kspart)
{
  __shared__ __align__(16) u16 smem[2 * 64 * 130];   // kT | vT, 33.3 KB
  u16 (*kT)[130] = (u16(*)[130])smem;
  u16 (*vT)[130] = (u16(*)[130])(smem + 64 * 130);
  float* red = (float*)smem;            // pitch 68; reused after MFMA (<=17.4KB)
  float* ksr = ((float*)smem) + 4352;   // 4 waves x 64 floats

  const int split = blockIdx.x, h = blockIdx.y, b = blockIdx.z;
  const int bh = b * HHEADS + h;
  const int tid = threadIdx.x, lane = tid & 63, w = tid >> 6;
  const size_t base = (size_t)b * NSEQ * EDIM + h * DHEAD;
  const int nbase = split * (NSEQ / KVSPLIT);   // 256 n per block

  float ksacc[8] = {0, 0, 0, 0, 0, 0, 0, 0};
  facc4 acc[4][4];
#pragma unroll
  for (int i = 0; i < 4; ++i)
#pragma unroll
    for (int j = 0; j < 4; ++j) acc[i][j] = (facc4){0.f, 0.f, 0.f, 0.f};

  const int e0 = (tid & 7) * 8;
  const int nl0 = tid >> 3;      // 0..31
  const int fr = lane & 15;
  const int quad = lane >> 4;

  for (int c = 0; c < 2; ++c) {
    const int nchunk = nbase + c * 128;
#pragma unroll
    for (int rep = 0; rep < 4; ++rep) {
      const int n = rep * 32 + nl0;
      const uint4 kd = *(const uint4*)(Km + base + (size_t)(nchunk + n) * EDIM + e0);
      const uint4 vd = *(const uint4*)(V  + base + (size_t)(nchunk + n) * EDIM + e0);
      const u16* pk = (const u16*)&kd;
      const u16* pv = (const u16*)&vd;
#pragma unroll
      for (int ii = 0; ii < 8; ++ii) {
        kT[e0 + ii][n] = pk[ii];
        ksacc[ii] += b2f(pk[ii]);
        vT[e0 + ii][n] = pv[ii];
      }
    }
    __syncthreads();
    const int kq2 = w * 32 + quad * 8;   // wave w contracts n in [w*32,(w+1)*32)
    frag8 af[4], bf[4];
#pragma unroll
    for (int i = 0; i < 4; ++i) af[i] = *(const frag8*)&kT[i * 16 + fr][kq2];
#pragma unroll
    for (int j = 0; j < 4; ++j) bf[j] = *(const frag8*)&vT[j * 16 + fr][kq2];
#pragma unroll
    for (int i = 0; i < 4; ++i)
#pragma unroll
      for (int j = 0; j < 4; ++j)
        acc[i][j] = __builtin_amdgcn_mfma_f32_16x16x32_bf16(af[i], bf[j], acc[i][j], 0, 0, 0);
    __syncthreads();
  }

  // rotated cross-wave reduction into red (pitch 68)
  for (int p = 0; p < 4; ++p) {
    const int j = (w + p) & 3;
#pragma unroll
    for (int i = 0; i < 4; ++i)
#pragma unroll
      for (int r = 0; r < 4; ++r) {
        const int d = i * 16 + quad * 4 + r;
        const int e = j * 16 + fr;
        if (p == 0) red[d * 68 + e] = acc[i][j][r];
        else        red[d * 68 + e] += acc[i][j][r];
      }
    __syncthreads();
  }

  // write 64x64 partial (coalesced)
  const size_t pbase = ((size_t)bh * KVSPLIT + split) * 4096;
#pragma unroll
  for (int ii = 0; ii < 16; ++ii) {
    const int idx = tid + ii * 256;
    partials[pbase + idx] = red[(idx >> 6) * 68 + (idx & 63)];
  }

  // k_sum partial: shuffle-tree over stride-8 lane groups, then cross-wave LDS
#pragma unroll
  for (int ii = 0; ii < 8; ++ii) {
    ksacc[ii] += __shfl_down(ksacc[ii], 32, 64);
    ksacc[ii] += __shfl_down(ksacc[ii], 16, 64);
    ksacc[ii] += __shfl_down(ksacc[ii], 8, 64);
  }
  if (lane < 8) {
#pragma unroll
    for (int ii = 0; ii < 8; ++ii) ksr[w * 64 + lane * 8 + ii] = ksacc[ii];
  }
  __syncthreads();
  if (tid < 64)
    kspart[((size_t)bh * KVSPLIT + split) * 64 + tid] =
        ksr[tid] + ksr[64 + tid] + ksr[128 + tid] + ksr[192 + tid];
}

// Stage 2: reduce KVSPLIT partial slots -> KV f32 [d][e] and Ks.
__global__ __launch_bounds__(256) void kv_reduce(
    const float* __restrict__ partials, const float* __restrict__ kspart,
    float* __restrict__ KV, float* __restrict__ Ks)
{
  const int qt = blockIdx.x;   // 0..3
  const int bh = blockIdx.y;   // 0..63
  const int tid = threadIdx.x;
#pragma unroll
  for (int ii = 0; ii < 4; ++ii) {
    const int idx = qt * 1024 + ii * 256 + tid;
    float s = 0.f;
#pragma unroll
    for (int sp = 0; sp < KVSPLIT; ++sp)
      s += partials[((size_t)bh * KVSPLIT + sp) * 4096 + idx];
    KV[(size_t)bh * 4096 + idx] = s;
  }
  if (qt == 0 && tid < 64) {
    float s = 0.f;
#pragma unroll
    for (int sp = 0; sp < KVSPLIT; ++sp)
      s += kspart[((size_t)bh * KVSPLIT + sp) * 64 + tid];
    Ks[bh * 64 + tid] = s;
  }
}

// ---------------------------------------------------------------------------
// attn[b,q,h,e] = (sum_d q[b,q,h,d]*kv[bh][d][e]) / (q . ksum[bh] + 1e-8)
// ---------------------------------------------------------------------------
__global__ __launch_bounds__(256) void attn_nd(
    const u16* __restrict__ Q, const float* __restrict__ KV,
    const float* __restrict__ Ks, u16* __restrict__ O)
{
  __shared__ __align__(16) u16 kvT[64][72];  // [e][d], pad +8
  __shared__ float ks_s[64];
  __shared__ float den_s[4][16];
  const int qt = blockIdx.x, h = blockIdx.y, b = blockIdx.z;
  const int bh = b * HHEADS + h;
  const int tid = threadIdx.x, lane = tid & 63, w = tid >> 6;
  const float* kvp = KV + (size_t)bh * 4096;
#pragma unroll
  for (int ii = 0; ii < 16; ++ii) {
    const int idx = tid + ii * 256;          // idx = d*64+e
    kvT[idx & 63][idx >> 6] = f2b(kvp[idx]);
  }
  if (tid < 64) ks_s[tid] = Ks[bh * 64 + tid];
  __syncthreads();

  const int fr = lane & 15;
  const int q8 = (lane >> 4) * 8;
  const u16* qp = Q + (size_t)(b * NSEQ + qt * 64 + w * 16 + fr) * EDIM + h * DHEAD;
  const frag8 a0 = *(const frag8*)(qp + q8);
  const frag8 a1 = *(const frag8*)(qp + 32 + q8);

  const u16* a0u = (const u16*)&a0;
  const u16* a1u = (const u16*)&a1;
  float den = 0.f;
#pragma unroll
  for (int j = 0; j < 8; ++j)
    den += b2f(a0u[j]) * ks_s[q8 + j] + b2f(a1u[j]) * ks_s[32 + q8 + j];
  den += __shfl_xor(den, 16, 64);
  den += __shfl_xor(den, 32, 64);
  if (lane < 16) den_s[w][lane] = den + 1e-8f;

  facc4 acc[4];
#pragma unroll
  for (int j = 0; j < 4; ++j) acc[j] = (facc4){0.f, 0.f, 0.f, 0.f};
#pragma unroll
  for (int j = 0; j < 4; ++j) {
    const frag8 b0 = *(const frag8*)&kvT[j * 16 + fr][q8];
    const frag8 b1 = *(const frag8*)&kvT[j * 16 + fr][32 + q8];
    acc[j] = __builtin_amdgcn_mfma_f32_16x16x32_bf16(a0, b0, acc[j], 0, 0, 0);
    acc[j] = __builtin_amdgcn_mfma_f32_16x16x32_bf16(a1, b1, acc[j], 0, 0, 0);
  }
  __syncthreads();
#pragma unroll
  for (int r = 0; r < 4; ++r) {
    const int rq = (lane >> 4) * 4 + r;
    const float dv = den_s[w][rq];
    const size_t orow = (size_t)(b * NSEQ + qt * 64 + w * 16 + rq) * EDIM + h * DHEAD;
#pragma unroll
    for (int j = 0; j < 4; ++j)
      O[orow + j * 16 + fr] = f2b(acc[j][r] / dv);
  }
}

// ---------------------------------------------------------------------------
extern "C" void kernel_launch(void* const* d_in, const int* in_sizes, int n_in,
                              void* d_out, int out_size, void* d_ws, size_t ws_size,
                              hipStream_t stream) {
  char* ws = (char*)d_ws;
  const size_t EH = (size_t)NTOK * EDIM;      // 16.78M elems
  unsigned* flag = (unsigned*)ws;             // 1 KB slot
  u16* Wqb  = (u16*)(ws + 1024);
  u16* Wkb  = Wqb + EDIM * EDIM;
  u16* Wvb  = Wkb + EDIM * EDIM;
  u16* Wob  = Wvb + EDIM * EDIM;
  u16* bqb  = Wob + EDIM * EDIM;
  u16* bkb  = bqb + 1024;
  u16* bvb  = bkb + 1024;
  u16* bob  = bvb + 1024;
  u16* gqb  = bob + 1024;
  u16* bEqb = gqb + 1024;
  u16* gkb  = bEqb + 1024;
  u16* bEkb = gkb + 1024;
  u16* Xin  = bEkb + 1024;    // f32-world staging; later attn output (both worlds)
  u16* preQ = Xin + EH;
  u16* preK = preQ + EH;
  u16* vbuf = preK + EH;
  float* partials = (float*)(vbuf + EH);              // 64*16*4096 f32 = 16MB
  float* kspart   = partials + (size_t)64 * KVSPLIT * 4096;  // 64*16*64 f32
  float* kvbuf    = kspart + (size_t)64 * KVSPLIT * 64;      // 64*4096 f32
  float* ksbuf    = kvbuf + (size_t)64 * 4096;               // 64*64 f32
  // total ws use ~160 MB

  const dim3 gg(256), tb(512);
  const int NW = EDIM * EDIM;

  detect_dtype<<<1, 64, 0, stream>>>((const u16*)d_in[0], flag);
  cvt_bf16<<<NW / 2048, 256, 0, stream>>>(d_in[3], Wqb, NW, flag);
  cvt_bf16<<<NW / 2048, 256, 0, stream>>>(d_in[5], Wkb, NW, flag);
  cvt_bf16<<<NW / 2048, 256, 0, stream>>>(d_in[7], Wvb, NW, flag);
  cvt_bf16<<<NW / 2048, 256, 0, stream>>>(d_in[9], Wob, NW, flag);
  Ptr8 p8;
  p8.s[0] = d_in[4];  p8.s[1] = d_in[6];  p8.s[2] = d_in[8];  p8.s[3] = d_in[10];
  p8.s[4] = d_in[11]; p8.s[5] = d_in[12]; p8.s[6] = d_in[13]; p8.s[7] = d_in[14];
  p8.d[0] = bqb; p8.d[1] = bkb; p8.d[2] = bvb; p8.d[3] = bob;
  p8.d[4] = gqb; p8.d[5] = bEqb; p8.d[6] = gkb; p8.d[7] = bEkb;
  cvt8<<<4, 256, 0, stream>>>(p8, flag);

  cvt_bf16<<<EH / 2048, 256, 0, stream>>>(d_in[0], Xin, (int)EH, flag);
  gemm256<<<gg, tb, 0, stream>>>(d_in[0], Xin, d_in[3], Wqb, bqb, preQ, flag, 0);
  cvt_bf16<<<EH / 2048, 256, 0, stream>>>(d_in[1], Xin, (int)EH, flag);
  gemm256<<<gg, tb, 0, stream>>>(d_in[1], Xin, d_in[5], Wkb, bkb, preK, flag, 0);
  cvt_bf16<<<EH / 2048, 256, 0, stream>>>(d_in[2], Xin, (int)EH, flag);
  gemm256<<<gg, tb, 0, stream>>>(d_in[2], Xin, d_in[7], Wvb, bvb, vbuf, flag, 0);

  ln_elu<<<NTOK, 256, 0, stream>>>(preQ, gqb, bEqb, preQ);   // in-place safe
  ln_elu<<<NTOK, 256, 0, stream>>>(preK, gkb, bEkb, preK);

  kv_partial<<<dim3(KVSPLIT, HHEADS, BB), dim3(256), 0, stream>>>(preK, vbuf, partials, kspart);
  kv_reduce<<<dim3(4, 64), dim3(256), 0, stream>>>(partials, kspart, kvbuf, ksbuf);
  attn_nd<<<dim3(NSEQ / 64, HHEADS, BB), dim3(256), 0, stream>>>(preQ, kvbuf, ksbuf, Xin);
  gemm256<<<gg, tb, 0, stream>>>(Xin, Xin, d_in[9], Wob, bob, (u16*)d_out, flag, 1);
}

// Round 6
// 525.289 us; speedup vs baseline: 1.0550x; 1.0284x over previous
//
#include <hip/hip_runtime.h>
#include <hip/hip_bf16.h>

// Problem constants
#define EDIM 1024
#define HHEADS 16
#define DHEAD 64
#define BB 4
#define NSEQ 4096
#define NTOK 16384   // BB*NSEQ
#define KVSPLIT 16

typedef unsigned short u16;
using frag8 = __attribute__((ext_vector_type(8))) short;   // 8 bf16 (4 VGPRs)
using facc4 = __attribute__((ext_vector_type(4))) float;   // 4 f32 acc

__device__ __forceinline__ float b2f(u16 u) {
  union { unsigned int i; float f; } c; c.i = ((unsigned int)u) << 16; return c.f;
}
__device__ __forceinline__ u16 f2b(float f) {
  __hip_bfloat16 h = __float2bfloat16(f);   // RNE
  union { __hip_bfloat16 h; u16 u; } c; c.h = h; return c.u;
}
__device__ __forceinline__ void gl2lds16(const void* g, void* l) {
  __builtin_amdgcn_global_load_lds(
      (const __attribute__((address_space(1))) unsigned int*)g,
      (__attribute__((address_space(3))) unsigned int*)l, 16, 0, 0);
}

// ---------------------------------------------------------------------------
// Dtype probe: flag[0]=1 -> inputs are bf16, 0 -> f32 (per reference).
// ---------------------------------------------------------------------------
__global__ void detect_dtype(const u16* __restrict__ src, unsigned* __restrict__ flag) {
  const int lane = threadIdx.x;                    // 64 threads
  const unsigned u = src[(size_t)lane * 200000];   // even u16 indices
  const unsigned e = (u >> 7) & 0xFF;
  const bool inl = (u == 0) || (e >= 100 && e <= 135);
  const unsigned long long m = __ballot(inl);
  if (lane == 0) flag[0] = (__popcll(m) >= 32) ? 1u : 0u;
}

// f32 -> bf16 conversion; NO-OP in bf16 world (GEMM reads raw ptr directly).
__global__ __launch_bounds__(256) void cvt_bf16(
    const void* __restrict__ src, u16* __restrict__ dst, int n,
    const unsigned* __restrict__ flag) {
  if (flag[0] == 1) return;
  const int i0 = (blockIdx.x * 256 + threadIdx.x) * 8;
  if (i0 >= n) return;
  const float4 a = ((const float4*)src)[i0 >> 2];
  const float4 b = ((const float4*)src)[(i0 >> 2) + 1];
  ushort4 lo, hi;
  lo.x = f2b(a.x); lo.y = f2b(a.y); lo.z = f2b(a.z); lo.w = f2b(a.w);
  hi.x = f2b(b.x); hi.y = f2b(b.y); hi.z = f2b(b.z); hi.w = f2b(b.w);
  ((ushort4*)dst)[i0 >> 2] = lo;
  ((ushort4*)dst)[(i0 >> 2) + 1] = hi;
}

// Convert 8 vectors of 1024 elements each (biases, gains, betas). Always runs.
struct Ptr8 { const void* s[8]; u16* d[8]; };
__global__ __launch_bounds__(256) void cvt8(Ptr8 p, const unsigned* __restrict__ flag) {
  const int t = blockIdx.x * 256 + threadIdx.x;    // 0..1023
  const int v = t >> 7;
  const int i0 = (t & 127) * 8;
  const void* s = p.s[v];
  u16* d = p.d[v];
  ushort4 lo, hi;
  if (flag[0] == 0) {
    const float4 a = ((const float4*)s)[i0 >> 2];
    const float4 b = ((const float4*)s)[(i0 >> 2) + 1];
    lo.x = f2b(a.x); lo.y = f2b(a.y); lo.z = f2b(a.z); lo.w = f2b(a.w);
    hi.x = f2b(b.x); hi.y = f2b(b.y); hi.z = f2b(b.z); hi.w = f2b(b.w);
  } else {
    lo = ((const ushort4*)s)[i0 >> 2];
    hi = ((const ushort4*)s)[(i0 >> 2) + 1];
  }
  ((ushort4*)d)[i0 >> 2] = lo;
  ((ushort4*)d)[(i0 >> 2) + 1] = hi;
}

// ---------------------------------------------------------------------------
// GEMM: C[M,1024] = A[M,1024] @ W[1024,1024]^T + bias (bf16 in, f32 acc).
// 256x256 tile, BK=64, 512 threads (8 waves, 2Mx4N), 8-phase counted-vmcnt
// schedule (T2 swizzle + T3/T4 + T5, per the m201 template).
//
// R5 edit (LDS-read reduction): A-fragments (af) are loaded only in QN=0
// phases and kept in registers through the matching QN=1 phase (same BUF,QM
// -> same data). This removes the 8 redundant ds_read_b128 per odd phase:
// 48 -> 32 reads per K-tile per wave (-33% LDS traffic, which R5 counters
// showed to be the dominant stall: MfmaUtil 24%, LDS ~31us of 53us).
// Sync structure (barriers, staging issue slots, vmcnt ledger) is UNCHANGED
// from the harness-verified R5 kernel.
//
// Schedule per iteration (tiles T=2i in buf0 phases 1-4, T+1 in buf1 phases
// 5-8; quadrant order q(0,0),q(0,1),q(1,0),q(1,1) per tile):
//   ph1: issue buf1.{A1,B1}(T+1)   ph3: issue buf0.A0(T+2)
//   ph4: issue buf0.B0(T+2), vmcnt(4)
//   ph5: issue buf0.{A1,B1}(T+2)   ph7: issue buf1.A0(T+3)
//   ph8: issue buf1.B0(T+3), vmcnt(4)
// ---------------------------------------------------------------------------
#define STA(BUF, QM, T)                                                       \
  gl2lds16(Ag + (size_t)(QM) * 64 * EDIM + (size_t)(T) * 64,                  \
           AsW + (BUF) * 16384 + (QM) * 8192);                                \
  gl2lds16(Ag + (size_t)(QM) * 64 * EDIM + 128 * EDIM + (size_t)(T) * 64,     \
           AsW + (BUF) * 16384 + (QM) * 8192 + 4096);

#define STB(BUF, QN, T)                                                       \
  gl2lds16(Bg + (size_t)(QN) * 32 * EDIM + (size_t)(T) * 64,                  \
           BsW + (BUF) * 16384 + (QN) * 8192);                                \
  gl2lds16(Bg + (size_t)(QN) * 32 * EDIM + 128 * EDIM + (size_t)(T) * 64,     \
           BsW + (BUF) * 16384 + (QN) * 8192 + 4096);

#define VM(N) asm volatile("s_waitcnt vmcnt(" #N ")" ::: "memory");

// LOADA=1: (re)load af from As[BUF][QM]; LOADA=0: reuse af from prior phase.
#define PH(BUF, QM, QN, LOADA, ISSUE, TAIL)                                   \
  {                                                                           \
    if (LOADA) {                                                              \
      _Pragma("unroll") for (int i = 0; i < 4; ++i) {                         \
        const u16* rp = &As[BUF][QM][wm * 64 + i * 16 + fr][0];               \
        af[i][0] = *(const frag8*)(rp + c0);                                  \
        af[i][1] = *(const frag8*)(rp + c1);                                  \
      }                                                                       \
    }                                                                         \
    frag8 bq[2][2];                                                           \
    _Pragma("unroll") for (int j = 0; j < 2; ++j) {                           \
      const u16* rp = &Bs[BUF][QN][wn * 32 + j * 16 + fr][0];                 \
      bq[j][0] = *(const frag8*)(rp + c0);                                    \
      bq[j][1] = *(const frag8*)(rp + c1);                                    \
    }                                                                         \
    ISSUE                                                                     \
    __builtin_amdgcn_s_barrier();                                             \
    asm volatile("s_waitcnt lgkmcnt(0)" ::: "memory");                        \
    __builtin_amdgcn_sched_barrier(0);                                        \
    __builtin_amdgcn_s_setprio(1);                                            \
    _Pragma("unroll") for (int kk = 0; kk < 2; ++kk)                          \
      _Pragma("unroll") for (int i = 0; i < 4; ++i)                           \
        _Pragma("unroll") for (int j = 0; j < 2; ++j)                         \
          acc[(QM) * 4 + i][(QN) * 2 + j] =                                   \
              __builtin_amdgcn_mfma_f32_16x16x32_bf16(                        \
                  af[i][kk], bq[j][kk], acc[(QM) * 4 + i][(QN) * 2 + j],      \
                  0, 0, 0);                                                   \
    __builtin_amdgcn_s_setprio(0);                                            \
    TAIL                                                                      \
    __builtin_amdgcn_s_barrier();                                             \
    __builtin_amdgcn_sched_barrier(0);                                        \
  }

__global__ __launch_bounds__(512, 2) void gemm256(
    const void* __restrict__ Araw, const u16* __restrict__ Acvt,
    const void* __restrict__ Wraw, const u16* __restrict__ Wcvt,
    const u16* __restrict__ bias, u16* __restrict__ C,
    const unsigned* __restrict__ flag, int outMode)
{
  __shared__ __align__(16) u16 As[2][2][128][64];   // 64 KiB
  __shared__ __align__(16) u16 Bs[2][2][128][64];   // 64 KiB

  const int tid  = threadIdx.x;
  const int lane = tid & 63;
  const int w    = tid >> 6;       // 0..7
  const int wm   = w >> 2;         // 0..1 (M half)
  const int wn   = w & 3;          // 0..3 (N quarter)

  // XCD-bijective swizzle (256 blocks, 256%8==0).
  const int bid0 = blockIdx.x;
  const int bid  = (bid0 & 7) * 32 + (bid0 >> 3);
  const int rowBase = (bid >> 2) * 256;
  const int colBase = (bid & 3) * 256;

  const bool bfw = (flag[0] == 1);
  const u16* A  = bfw ? (const u16*)Araw : Acvt;
  const u16* Wt = bfw ? (const u16*)Wraw : Wcvt;

  // Staging addressing (pre-swizzled global source; LDS linear dest).
  const int lr = w * 8 + (lane >> 3);               // row within 64-row op
  const int sc = 8 * ((lane & 7) ^ (lane >> 3));    // swizzled col (elems)
  const u16* Ag = A  + (size_t)(rowBase + lr) * EDIM + sc;
  const u16* Bg = Wt + (size_t)(colBase + (lr >> 5) * 64 + (lr & 31)) * EDIM + sc;
  u16* AsW = &As[0][0][w * 8][0];   // + buf*16384 + region*8192 + o*4096
  u16* BsW = &Bs[0][0][w * 8][0];

  // ds_read fragment addressing (16x16x32 A/B layout: row fr, k = qd*8+kk*32)
  const int fr = lane & 15;
  const int qd = lane >> 4;
  const int sw = fr & 7;
  const int c0 = 8 * (qd ^ sw);          // kk=0 swizzled col offset (elems)
  const int c1 = 8 * ((qd + 4) ^ sw);    // kk=1

  facc4 acc[8][4];
#pragma unroll
  for (int i = 0; i < 8; ++i)
#pragma unroll
    for (int j = 0; j < 4; ++j) acc[i][j] = (facc4){0.f, 0.f, 0.f, 0.f};

  frag8 af[4][2];   // A-frags, persist across the QN=0 -> QN=1 phase pair

  // Prologue: tile0 fully (8 ops), tile1 A0+B0 (4 ops); retire tile0.
  STA(0, 0, 0) STB(0, 0, 0) STA(0, 1, 0) STB(0, 1, 0)
  STA(1, 0, 1) STB(1, 0, 1)
  VM(4)
  __builtin_amdgcn_s_barrier();
  __builtin_amdgcn_sched_barrier(0);

#pragma unroll 1
  for (int it = 0; it < 7; ++it) {                  // tiles 0..13
    const int t1 = 2 * it + 1, t2 = t1 + 1, t3 = t1 + 2;
    PH(0, 0, 0, 1, STA(1, 1, t1) STB(1, 1, t1), )
    PH(0, 0, 1, 0, , )
    PH(0, 1, 0, 1, STA(0, 0, t2), )
    PH(0, 1, 1, 0, STB(0, 0, t2), VM(4))
    PH(1, 0, 0, 1, STA(0, 1, t2) STB(0, 1, t2), )
    PH(1, 0, 1, 0, , )
    PH(1, 1, 0, 1, STA(1, 0, t3), )
    PH(1, 1, 1, 0, STB(1, 0, t3), VM(4))
  }
  // Final pair: tiles 14 (buf0), 15 (buf1); drain at phase 4.
  PH(0, 0, 0, 1, STA(1, 1, 15) STB(1, 1, 15), )
  PH(0, 0, 1, 0, , )
  PH(0, 1, 0, 1, , )
  PH(0, 1, 1, 0, , VM(0))
  PH(1, 0, 0, 1, , )
  PH(1, 0, 1, 0, , )
  PH(1, 1, 0, 1, , )
  PH(1, 1, 1, 0, , )

  // Epilogue: bias + store (C/D layout: col=lane&15, row=quad*4+reg).
  const bool f32out = (outMode == 1) && !bfw;
  float* Cf = (float*)C;
  float bvv[4];
#pragma unroll
  for (int j = 0; j < 4; ++j)
    bvv[j] = b2f(bias[colBase + wn * 64 + j * 16 + fr]);
#pragma unroll
  for (int i = 0; i < 8; ++i) {
#pragma unroll
    for (int r = 0; r < 4; ++r) {
      const int row = rowBase + wm * 128 + i * 16 + qd * 4 + r;
      const size_t ro = (size_t)row * EDIM + colBase + wn * 64 + fr;
#pragma unroll
      for (int j = 0; j < 4; ++j) {
        const float val = acc[i][j][r] + bvv[j];
        if (f32out) Cf[ro + j * 16] = val;
        else        C[ro + j * 16]  = f2b(val);
      }
    }
  }
}

// ---------------------------------------------------------------------------
// LayerNorm (+g,beta) then elu+1, per row of 1024 (bf16 in/out, in-place OK).
// ---------------------------------------------------------------------------
__global__ __launch_bounds__(256) void ln_elu(
    const u16* __restrict__ X, const u16* __restrict__ g,
    const u16* __restrict__ beta, u16* __restrict__ Y)
{
  __shared__ float wsum[4], wsq[4];
  const int row = blockIdx.x, tid = threadIdx.x;
  const ushort4 xu = ((const ushort4*)(X + (size_t)row * EDIM))[tid];
  float x[4] = { b2f(xu.x), b2f(xu.y), b2f(xu.z), b2f(xu.w) };
  float s  = x[0] + x[1] + x[2] + x[3];
  float ss = x[0]*x[0] + x[1]*x[1] + x[2]*x[2] + x[3]*x[3];
#pragma unroll
  for (int off = 32; off > 0; off >>= 1) {
    s  += __shfl_down(s,  off, 64);
    ss += __shfl_down(ss, off, 64);
  }
  if ((tid & 63) == 0) { wsum[tid >> 6] = s; wsq[tid >> 6] = ss; }
  __syncthreads();
  const float S  = wsum[0] + wsum[1] + wsum[2] + wsum[3];
  const float SS = wsq[0] + wsq[1] + wsq[2] + wsq[3];
  const float mu  = S * (1.0f / EDIM);
  const float var = SS * (1.0f / EDIM) - mu * mu;
  const float rs  = rsqrtf(var + 1e-5f);
  const ushort4 gu = ((const ushort4*)g)[tid];
  const ushort4 bu = ((const ushort4*)beta)[tid];
  float gg[4] = { b2f(gu.x), b2f(gu.y), b2f(gu.z), b2f(gu.w) };
  float bb[4] = { b2f(bu.x), b2f(bu.y), b2f(bu.z), b2f(bu.w) };
  ushort4 out;
  u16 o[4];
#pragma unroll
  for (int c = 0; c < 4; ++c) {
    float y = (x[c] - mu) * rs * gg[c] + bb[c];
    y = (y > 0.f) ? (y + 1.f) : __expf(y);   // elu(y)+1
    o[c] = f2b(y);
  }
  out.x = o[0]; out.y = o[1]; out.z = o[2]; out.w = o[3];
  ((ushort4*)(Y + (size_t)row * EDIM))[tid] = out;
}

// ---------------------------------------------------------------------------
// Stage 1: per-(split,h,b) partial kv_sum (64x64 f32) + partial k_sum -> own
// global slots (NO atomics). 256 n per block, 2 chunks of 128.
// ---------------------------------------------------------------------------
__global__ __launch_bounds__(256) void kv_partial(
    const u16* __restrict__ Km, const u16* __restrict__ V,
    float* __restrict__ partials, float* __restrict__ kspart)
{
  __shared__ __align__(16) u16 smem[2 * 64 * 130];   // kT | vT, 33.3 KB
  u16 (*kT)[130] = (u16(*)[130])smem;
  u16 (*vT)[130] = (u16(*)[130])(smem + 64 * 130);
  float* red = (float*)smem;            // pitch 68; reused after MFMA (<=17.4KB)
  float* ksr = ((float*)smem) + 4352;   // 4 waves x 64 floats

  const int split = blockIdx.x, h = blockIdx.y, b = blockIdx.z;
  const int bh = b * HHEADS + h;
  const int tid = threadIdx.x, lane = tid & 63, w = tid >> 6;
  const size_t base = (size_t)b * NSEQ * EDIM + h * DHEAD;
  const int nbase = split * (NSEQ / KVSPLIT);   // 256 n per block

  float ksacc[8] = {0, 0, 0, 0, 0, 0, 0, 0};
  facc4 acc[4][4];
#pragma unroll
  for (int i = 0; i < 4; ++i)
#pragma unroll
    for (int j = 0; j < 4; ++j) acc[i][j] = (facc4){0.f, 0.f, 0.f, 0.f};

  const int e0 = (tid & 7) * 8;
  const int nl0 = tid >> 3;      // 0..31
  const int fr = lane & 15;
  const int quad = lane >> 4;

  for (int c = 0; c < 2; ++c) {
    const int nchunk = nbase + c * 128;
#pragma unroll
    for (int rep = 0; rep < 4; ++rep) {
      const int n = rep * 32 + nl0;
      const uint4 kd = *(const uint4*)(Km + base + (size_t)(nchunk + n) * EDIM + e0);
      const uint4 vd = *(const uint4*)(V  + base + (size_t)(nchunk + n) * EDIM + e0);
      const u16* pk = (const u16*)&kd;
      const u16* pv = (const u16*)&vd;
#pragma unroll
      for (int ii = 0; ii < 8; ++ii) {
        kT[e0 + ii][n] = pk[ii];
        ksacc[ii] += b2f(pk[ii]);
        vT[e0 + ii][n] = pv[ii];
      }
    }
    __syncthreads();
    const int kq2 = w * 32 + quad * 8;   // wave w contracts n in [w*32,(w+1)*32)
    frag8 af[4], bf[4];
#pragma unroll
    for (int i = 0; i < 4; ++i) af[i] = *(const frag8*)&kT[i * 16 + fr][kq2];
#pragma unroll
    for (int j = 0; j < 4; ++j) bf[j] = *(const frag8*)&vT[j * 16 + fr][kq2];
#pragma unroll
    for (int i = 0; i < 4; ++i)
#pragma unroll
      for (int j = 0; j < 4; ++j)
        acc[i][j] = __builtin_amdgcn_mfma_f32_16x16x32_bf16(af[i], bf[j], acc[i][j], 0, 0, 0);
    __syncthreads();
  }

  // rotated cross-wave reduction into red (pitch 68)
  for (int p = 0; p < 4; ++p) {
    const int j = (w + p) & 3;
#pragma unroll
    for (int i = 0; i < 4; ++i)
#pragma unroll
      for (int r = 0; r < 4; ++r) {
        const int d = i * 16 + quad * 4 + r;
        const int e = j * 16 + fr;
        if (p == 0) red[d * 68 + e] = acc[i][j][r];
        else        red[d * 68 + e] += acc[i][j][r];
      }
    __syncthreads();
  }

  // write 64x64 partial (coalesced)
  const size_t pbase = ((size_t)bh * KVSPLIT + split) * 4096;
#pragma unroll
  for (int ii = 0; ii < 16; ++ii) {
    const int idx = tid + ii * 256;
    partials[pbase + idx] = red[(idx >> 6) * 68 + (idx & 63)];
  }

  // k_sum partial: shuffle-tree over stride-8 lane groups, then cross-wave LDS
#pragma unroll
  for (int ii = 0; ii < 8; ++ii) {
    ksacc[ii] += __shfl_down(ksacc[ii], 32, 64);
    ksacc[ii] += __shfl_down(ksacc[ii], 16, 64);
    ksacc[ii] += __shfl_down(ksacc[ii], 8, 64);
  }
  if (lane < 8) {
#pragma unroll
    for (int ii = 0; ii < 8; ++ii) ksr[w * 64 + lane * 8 + ii] = ksacc[ii];
  }
  __syncthreads();
  if (tid < 64)
    kspart[((size_t)bh * KVSPLIT + split) * 64 + tid] =
        ksr[tid] + ksr[64 + tid] + ksr[128 + tid] + ksr[192 + tid];
}

// Stage 2: reduce KVSPLIT partial slots -> KV f32 [d][e] and Ks.
__global__ __launch_bounds__(256) void kv_reduce(
    const float* __restrict__ partials, const float* __restrict__ kspart,
    float* __restrict__ KV, float* __restrict__ Ks)
{
  const int qt = blockIdx.x;   // 0..3
  const int bh = blockIdx.y;   // 0..63
  const int tid = threadIdx.x;
#pragma unroll
  for (int ii = 0; ii < 4; ++ii) {
    const int idx = qt * 1024 + ii * 256 + tid;
    float s = 0.f;
#pragma unroll
    for (int sp = 0; sp < KVSPLIT; ++sp)
      s += partials[((size_t)bh * KVSPLIT + sp) * 4096 + idx];
    KV[(size_t)bh * 4096 + idx] = s;
  }
  if (qt == 0 && tid < 64) {
    float s = 0.f;
#pragma unroll
    for (int sp = 0; sp < KVSPLIT; ++sp)
      s += kspart[((size_t)bh * KVSPLIT + sp) * 64 + tid];
    Ks[bh * 64 + tid] = s;
  }
}

// ---------------------------------------------------------------------------
// attn[b,q,h,e] = (sum_d q[b,q,h,d]*kv[bh][d][e]) / (q . ksum[bh] + 1e-8)
// ---------------------------------------------------------------------------
__global__ __launch_bounds__(256) void attn_nd(
    const u16* __restrict__ Q, const float* __restrict__ KV,
    const float* __restrict__ Ks, u16* __restrict__ O)
{
  __shared__ __align__(16) u16 kvT[64][72];  // [e][d], pad +8
  __shared__ float ks_s[64];
  __shared__ float den_s[4][16];
  const int qt = blockIdx.x, h = blockIdx.y, b = blockIdx.z;
  const int bh = b * HHEADS + h;
  const int tid = threadIdx.x, lane = tid & 63, w = tid >> 6;
  const float* kvp = KV + (size_t)bh * 4096;
#pragma unroll
  for (int ii = 0; ii < 16; ++ii) {
    const int idx = tid + ii * 256;          // idx = d*64+e
    kvT[idx & 63][idx >> 6] = f2b(kvp[idx]);
  }
  if (tid < 64) ks_s[tid] = Ks[bh * 64 + tid];
  __syncthreads();

  const int fr = lane & 15;
  const int q8 = (lane >> 4) * 8;
  const u16* qp = Q + (size_t)(b * NSEQ + qt * 64 + w * 16 + fr) * EDIM + h * DHEAD;
  const frag8 a0 = *(const frag8*)(qp + q8);
  const frag8 a1 = *(const frag8*)(qp + 32 + q8);

  const u16* a0u = (const u16*)&a0;
  const u16* a1u = (const u16*)&a1;
  float den = 0.f;
#pragma unroll
  for (int j = 0; j < 8; ++j)
    den += b2f(a0u[j]) * ks_s[q8 + j] + b2f(a1u[j]) * ks_s[32 + q8 + j];
  den += __shfl_xor(den, 16, 64);
  den += __shfl_xor(den, 32, 64);
  if (lane < 16) den_s[w][lane] = den + 1e-8f;

  facc4 acc[4];
#pragma unroll
  for (int j = 0; j < 4; ++j) acc[j] = (facc4){0.f, 0.f, 0.f, 0.f};
#pragma unroll
  for (int j = 0; j < 4; ++j) {
    const frag8 b0 = *(const frag8*)&kvT[j * 16 + fr][q8];
    const frag8 b1 = *(const frag8*)&kvT[j * 16 + fr][32 + q8];
    acc[j] = __builtin_amdgcn_mfma_f32_16x16x32_bf16(a0, b0, acc[j], 0, 0, 0);
    acc[j] = __builtin_amdgcn_mfma_f32_16x16x32_bf16(a1, b1, acc[j], 0, 0, 0);
  }
  __syncthreads();
#pragma unroll
  for (int r = 0; r < 4; ++r) {
    const int rq = (lane >> 4) * 4 + r;
    const float dv = den_s[w][rq];
    const size_t orow = (size_t)(b * NSEQ + qt * 64 + w * 16 + rq) * EDIM + h * DHEAD;
#pragma unroll
    for (int j = 0; j < 4; ++j)
      O[orow + j * 16 + fr] = f2b(acc[j][r] / dv);
  }
}

// ---------------------------------------------------------------------------
extern "C" void kernel_launch(void* const* d_in, const int* in_sizes, int n_in,
                              void* d_out, int out_size, void* d_ws, size_t ws_size,
                              hipStream_t stream) {
  char* ws = (char*)d_ws;
  const size_t EH = (size_t)NTOK * EDIM;      // 16.78M elems
  unsigned* flag = (unsigned*)ws;             // 1 KB slot
  u16* Wqb  = (u16*)(ws + 1024);
  u16* Wkb  = Wqb + EDIM * EDIM;
  u16* Wvb  = Wkb + EDIM * EDIM;
  u16* Wob  = Wvb + EDIM * EDIM;
  u16* bqb  = Wob + EDIM * EDIM;
  u16* bkb  = bqb + 1024;
  u16* bvb  = bkb + 1024;
  u16* bob  = bvb + 1024;
  u16* gqb  = bob + 1024;
  u16* bEqb = gqb + 1024;
  u16* gkb  = bEqb + 1024;
  u16* bEkb = gkb + 1024;
  u16* Xin  = bEkb + 1024;    // f32-world staging; later attn output (both worlds)
  u16* preQ = Xin + EH;
  u16* preK = preQ + EH;
  u16* vbuf = preK + EH;
  float* partials = (float*)(vbuf + EH);              // 64*16*4096 f32 = 16MB
  float* kspart   = partials + (size_t)64 * KVSPLIT * 4096;  // 64*16*64 f32
  float* kvbuf    = kspart + (size_t)64 * KVSPLIT * 64;      // 64*4096 f32
  float* ksbuf    = kvbuf + (size_t)64 * 4096;               // 64*64 f32
  // total ws use ~160 MB

  const dim3 gg(256), tb(512);
  const int NW = EDIM * EDIM;

  detect_dtype<<<1, 64, 0, stream>>>((const u16*)d_in[0], flag);
  cvt_bf16<<<NW / 2048, 256, 0, stream>>>(d_in[3], Wqb, NW, flag);
  cvt_bf16<<<NW / 2048, 256, 0, stream>>>(d_in[5], Wkb, NW, flag);
  cvt_bf16<<<NW / 2048, 256, 0, stream>>>(d_in[7], Wvb, NW, flag);
  cvt_bf16<<<NW / 2048, 256, 0, stream>>>(d_in[9], Wob, NW, flag);
  Ptr8 p8;
  p8.s[0] = d_in[4];  p8.s[1] = d_in[6];  p8.s[2] = d_in[8];  p8.s[3] = d_in[10];
  p8.s[4] = d_in[11]; p8.s[5] = d_in[12]; p8.s[6] = d_in[13]; p8.s[7] = d_in[14];
  p8.d[0] = bqb; p8.d[1] = bkb; p8.d[2] = bvb; p8.d[3] = bob;
  p8.d[4] = gqb; p8.d[5] = bEqb; p8.d[6] = gkb; p8.d[7] = bEkb;
  cvt8<<<4, 256, 0, stream>>>(p8, flag);

  cvt_bf16<<<EH / 2048, 256, 0, stream>>>(d_in[0], Xin, (int)EH, flag);
  gemm256<<<gg, tb, 0, stream>>>(d_in[0], Xin, d_in[3], Wqb, bqb, preQ, flag, 0);
  cvt_bf16<<<EH / 2048, 256, 0, stream>>>(d_in[1], Xin, (int)EH, flag);
  gemm256<<<gg, tb, 0, stream>>>(d_in[1], Xin, d_in[5], Wkb, bkb, preK, flag, 0);
  cvt_bf16<<<EH / 2048, 256, 0, stream>>>(d_in[2], Xin, (int)EH, flag);
  gemm256<<<gg, tb, 0, stream>>>(d_in[2], Xin, d_in[7], Wvb, bvb, vbuf, flag, 0);

  ln_elu<<<NTOK, 256, 0, stream>>>(preQ, gqb, bEqb, preQ);   // in-place safe
  ln_elu<<<NTOK, 256, 0, stream>>>(preK, gkb, bEkb, preK);

  kv_partial<<<dim3(KVSPLIT, HHEADS, BB), dim3(256), 0, stream>>>(preK, vbuf, partials, kspart);
  kv_reduce<<<dim3(4, 64), dim3(256), 0, stream>>>(partials, kspart, kvbuf, ksbuf);
  attn_nd<<<dim3(NSEQ / 64, HHEADS, BB), dim3(256), 0, stream>>>(preQ, kvbuf, ksbuf, Xin);
  gemm256<<<gg, tb, 0, stream>>>(Xin, Xin, d_in[9], Wob, bob, (u16*)d_out, flag, 1);
}

// Round 7
// 518.291 us; speedup vs baseline: 1.0692x; 1.0135x over previous
//
#include <hip/hip_runtime.h>
#include <hip/hip_bf16.h>

// Problem constants
#define EDIM 1024
#define HHEADS 16
#define DHEAD 64
#define BB 4
#define NSEQ 4096
#define NTOK 16384   // BB*NSEQ
#define KVSPLIT 16

typedef unsigned short u16;
using frag8 = __attribute__((ext_vector_type(8))) short;   // 8 bf16 (4 VGPRs)
using facc4 = __attribute__((ext_vector_type(4))) float;   // 4 f32 acc

__device__ __forceinline__ float b2f(u16 u) {
  union { unsigned int i; float f; } c; c.i = ((unsigned int)u) << 16; return c.f;
}
__device__ __forceinline__ u16 f2b(float f) {
  __hip_bfloat16 h = __float2bfloat16(f);   // RNE
  union { __hip_bfloat16 h; u16 u; } c; c.h = h; return c.u;
}
__device__ __forceinline__ void gl2lds16(const void* g, void* l) {
  __builtin_amdgcn_global_load_lds(
      (const __attribute__((address_space(1))) unsigned int*)g,
      (__attribute__((address_space(3))) unsigned int*)l, 16, 0, 0);
}

// ---------------------------------------------------------------------------
// Dtype probe: flag[0]=1 -> inputs are bf16, 0 -> f32 (per reference).
// ---------------------------------------------------------------------------
__global__ void detect_dtype(const u16* __restrict__ src, unsigned* __restrict__ flag) {
  const int lane = threadIdx.x;                    // 64 threads
  const unsigned u = src[(size_t)lane * 200000];   // even u16 indices
  const unsigned e = (u >> 7) & 0xFF;
  const bool inl = (u == 0) || (e >= 100 && e <= 135);
  const unsigned long long m = __ballot(inl);
  if (lane == 0) flag[0] = (__popcll(m) >= 32) ? 1u : 0u;
}

// f32 -> bf16 conversion; NO-OP in bf16 world (GEMM reads raw ptr directly).
__global__ __launch_bounds__(256) void cvt_bf16(
    const void* __restrict__ src, u16* __restrict__ dst, int n,
    const unsigned* __restrict__ flag) {
  if (flag[0] == 1) return;
  const int i0 = (blockIdx.x * 256 + threadIdx.x) * 8;
  if (i0 >= n) return;
  const float4 a = ((const float4*)src)[i0 >> 2];
  const float4 b = ((const float4*)src)[(i0 >> 2) + 1];
  ushort4 lo, hi;
  lo.x = f2b(a.x); lo.y = f2b(a.y); lo.z = f2b(a.z); lo.w = f2b(a.w);
  hi.x = f2b(b.x); hi.y = f2b(b.y); hi.z = f2b(b.z); hi.w = f2b(b.w);
  ((ushort4*)dst)[i0 >> 2] = lo;
  ((ushort4*)dst)[(i0 >> 2) + 1] = hi;
}

// Convert 8 vectors of 1024 elements each (biases, gains, betas). Always runs.
struct Ptr8 { const void* s[8]; u16* d[8]; };
__global__ __launch_bounds__(256) void cvt8(Ptr8 p, const unsigned* __restrict__ flag) {
  const int t = blockIdx.x * 256 + threadIdx.x;    // 0..1023
  const int v = t >> 7;
  const int i0 = (t & 127) * 8;
  const void* s = p.s[v];
  u16* d = p.d[v];
  ushort4 lo, hi;
  if (flag[0] == 0) {
    const float4 a = ((const float4*)s)[i0 >> 2];
    const float4 b = ((const float4*)s)[(i0 >> 2) + 1];
    lo.x = f2b(a.x); lo.y = f2b(a.y); lo.z = f2b(a.z); lo.w = f2b(a.w);
    hi.x = f2b(b.x); hi.y = f2b(b.y); hi.z = f2b(b.z); hi.w = f2b(b.w);
  } else {
    lo = ((const ushort4*)s)[i0 >> 2];
    hi = ((const ushort4*)s)[(i0 >> 2) + 1];
  }
  ((ushort4*)d)[i0 >> 2] = lo;
  ((ushort4*)d)[(i0 >> 2) + 1] = hi;
}

// ---------------------------------------------------------------------------
// GEMM: C[M,1024] = A[M,1024] @ W[1024,1024]^T + bias (bf16 in, f32 acc).
// 256x256 tile, BK=64, 512 threads (8 waves, 2Mx4N).
//
// R7: 4-phase schedule (merged QN0/QN1 phase pairs of the verified 8-phase).
// Per phase (BUF,QM): read A-frags (8 ds_read_b128) [+ B-frags 8 on QM0
// phases; B persists in regs through the QM1 phase], staging issue, barrier,
// lgkmcnt(0), 32 MFMA, tail, barrier. Halves barrier count (128->64) and
// per-phase drains; B reg-caching cuts ds_reads 32->24 per tile per wave.
// R6 counters showed phase overhead + LDS-read serialization as the stall
// (MfmaUtil 24%, VALUBusy 10%, conflicts 0).
//
// Ledger (per wave, 4 ops per issue group; VM(4) at nph2/nph4 tails):
//   invariant at nph1 entry: outstanding = {P4(i-1)} = 4
//   nph1: read buf0.{A0,B0,B1}(2i)   issue P1=buf1.{A1,B1}(2i+1)  -> 8
//   nph2: read buf0.A1(2i)           issue P2=buf0.{A0,B0}(2i+2)  -> 12
//         VM(4) retires P4(i-1),P1(i)
//   nph3: read buf1.{A0,B0,B1}(2i+1) issue P3=buf0.{A1,B1}(2i+2)  -> 8
//   nph4: read buf1.A1(2i+1)         issue P4=buf1.{A0,B0}(2i+3)  -> 12
//         VM(4) retires P2(i),P3(i)
// Every read's staging retired by the VM+barrier preceding it; every issue
// lands >=1 barrier after its region's last read drained (B reads confined
// to QM0 phases by the reg-cache, which keeps P2/P4 issues WAR-safe).
// Final pair drains with VM(0) at nph2 tail.
// ---------------------------------------------------------------------------
#define STA(BUF, QM, T)                                                       \
  gl2lds16(Ag + (size_t)(QM) * 64 * EDIM + (size_t)(T) * 64,                  \
           AsW + (BUF) * 16384 + (QM) * 8192);                                \
  gl2lds16(Ag + (size_t)(QM) * 64 * EDIM + 128 * EDIM + (size_t)(T) * 64,     \
           AsW + (BUF) * 16384 + (QM) * 8192 + 4096);

#define STB(BUF, QN, T)                                                       \
  gl2lds16(Bg + (size_t)(QN) * 32 * EDIM + (size_t)(T) * 64,                  \
           BsW + (BUF) * 16384 + (QN) * 8192);                                \
  gl2lds16(Bg + (size_t)(QN) * 32 * EDIM + 128 * EDIM + (size_t)(T) * 64,     \
           BsW + (BUF) * 16384 + (QN) * 8192 + 4096);

#define VM(N) asm volatile("s_waitcnt vmcnt(" #N ")" ::: "memory");

// One 4-phase step: A-frags always loaded; B-frags loaded when LOADB=1
// (QM0 phases) and reused from registers in the QM1 phase of the same BUF.
#define PH4(BUF, QM, LOADB, ISSUE, TAIL)                                      \
  {                                                                           \
    _Pragma("unroll") for (int i = 0; i < 4; ++i) {                           \
      const u16* rp = &As[BUF][QM][wm * 64 + i * 16 + fr][0];                 \
      af[i][0] = *(const frag8*)(rp + c0);                                    \
      af[i][1] = *(const frag8*)(rp + c1);                                    \
    }                                                                         \
    if (LOADB) {                                                              \
      _Pragma("unroll") for (int j = 0; j < 4; ++j) {                         \
        const u16* rp = &Bs[BUF][j >> 1][wn * 32 + (j & 1) * 16 + fr][0];     \
        bq[j][0] = *(const frag8*)(rp + c0);                                  \
        bq[j][1] = *(const frag8*)(rp + c1);                                  \
      }                                                                       \
    }                                                                         \
    ISSUE                                                                     \
    __builtin_amdgcn_s_barrier();                                             \
    asm volatile("s_waitcnt lgkmcnt(0)" ::: "memory");                        \
    __builtin_amdgcn_sched_barrier(0);                                        \
    __builtin_amdgcn_s_setprio(1);                                            \
    _Pragma("unroll") for (int kk = 0; kk < 2; ++kk)                          \
      _Pragma("unroll") for (int i = 0; i < 4; ++i)                           \
        _Pragma("unroll") for (int j = 0; j < 4; ++j)                         \
          acc[(QM) * 4 + i][j] =                                              \
              __builtin_amdgcn_mfma_f32_16x16x32_bf16(                        \
                  af[i][kk], bq[j][kk], acc[(QM) * 4 + i][j], 0, 0, 0);       \
    __builtin_amdgcn_s_setprio(0);                                            \
    TAIL                                                                      \
    __builtin_amdgcn_s_barrier();                                             \
    __builtin_amdgcn_sched_barrier(0);                                        \
  }

__global__ __launch_bounds__(512, 2) void gemm256(
    const void* __restrict__ Araw, const u16* __restrict__ Acvt,
    const void* __restrict__ Wraw, const u16* __restrict__ Wcvt,
    const u16* __restrict__ bias, u16* __restrict__ C,
    const unsigned* __restrict__ flag, int outMode)
{
  __shared__ __align__(16) u16 As[2][2][128][64];   // 64 KiB
  __shared__ __align__(16) u16 Bs[2][2][128][64];   // 64 KiB

  const int tid  = threadIdx.x;
  const int lane = tid & 63;
  const int w    = tid >> 6;       // 0..7
  const int wm   = w >> 2;         // 0..1 (M half)
  const int wn   = w & 3;          // 0..3 (N quarter)

  // XCD-bijective swizzle (256 blocks, 256%8==0).
  const int bid0 = blockIdx.x;
  const int bid  = (bid0 & 7) * 32 + (bid0 >> 3);
  const int rowBase = (bid >> 2) * 256;
  const int colBase = (bid & 3) * 256;

  const bool bfw = (flag[0] == 1);
  const u16* A  = bfw ? (const u16*)Araw : Acvt;
  const u16* Wt = bfw ? (const u16*)Wraw : Wcvt;

  // Staging addressing (pre-swizzled global source; LDS linear dest).
  const int lr = w * 8 + (lane >> 3);               // row within 64-row op
  const int sc = 8 * ((lane & 7) ^ (lane >> 3));    // swizzled col (elems)
  const u16* Ag = A  + (size_t)(rowBase + lr) * EDIM + sc;
  const u16* Bg = Wt + (size_t)(colBase + (lr >> 5) * 64 + (lr & 31)) * EDIM + sc;
  u16* AsW = &As[0][0][w * 8][0];   // + buf*16384 + region*8192 + o*4096
  u16* BsW = &Bs[0][0][w * 8][0];

  // ds_read fragment addressing (16x16x32 A/B layout: row fr, k = qd*8+kk*32)
  const int fr = lane & 15;
  const int qd = lane >> 4;
  const int sw = fr & 7;
  const int c0 = 8 * (qd ^ sw);          // kk=0 swizzled col offset (elems)
  const int c1 = 8 * ((qd + 4) ^ sw);    // kk=1

  facc4 acc[8][4];
#pragma unroll
  for (int i = 0; i < 8; ++i)
#pragma unroll
    for (int j = 0; j < 4; ++j) acc[i][j] = (facc4){0.f, 0.f, 0.f, 0.f};

  frag8 af[4][2];   // A-frags (per phase)
  frag8 bq[4][2];   // B-frags, persist across the QM0 -> QM1 phase pair

  // Prologue: tile0 fully (8 ops), tile1 A0+B0 (4 ops); retire tile0.
  STA(0, 0, 0) STB(0, 0, 0) STA(0, 1, 0) STB(0, 1, 0)
  STA(1, 0, 1) STB(1, 0, 1)
  VM(4)
  __builtin_amdgcn_s_barrier();
  __builtin_amdgcn_sched_barrier(0);

#pragma unroll 1
  for (int it = 0; it < 7; ++it) {                  // tiles 0..13
    const int t1 = 2 * it + 1, t2 = t1 + 1, t3 = t1 + 2;
    PH4(0, 0, 1, STA(1, 1, t1) STB(1, 1, t1), )
    PH4(0, 1, 0, STA(0, 0, t2) STB(0, 0, t2), VM(4))
    PH4(1, 0, 1, STA(0, 1, t2) STB(0, 1, t2), )
    PH4(1, 1, 0, STA(1, 0, t3) STB(1, 0, t3), VM(4))
  }
  // Final pair: tiles 14 (buf0), 15 (buf1); drain at nph2.
  PH4(0, 0, 1, STA(1, 1, 15) STB(1, 1, 15), )
  PH4(0, 1, 0, , VM(0))
  PH4(1, 0, 1, , )
  PH4(1, 1, 0, , )

  // Epilogue: bias + store (C/D layout: col=lane&15, row=quad*4+reg).
  const bool f32out = (outMode == 1) && !bfw;
  float* Cf = (float*)C;
  float bvv[4];
#pragma unroll
  for (int j = 0; j < 4; ++j)
    bvv[j] = b2f(bias[colBase + wn * 64 + j * 16 + fr]);
#pragma unroll
  for (int i = 0; i < 8; ++i) {
#pragma unroll
    for (int r = 0; r < 4; ++r) {
      const int row = rowBase + wm * 128 + i * 16 + qd * 4 + r;
      const size_t ro = (size_t)row * EDIM + colBase + wn * 64 + fr;
#pragma unroll
      for (int j = 0; j < 4; ++j) {
        const float val = acc[i][j][r] + bvv[j];
        if (f32out) Cf[ro + j * 16] = val;
        else        C[ro + j * 16]  = f2b(val);
      }
    }
  }
}

// ---------------------------------------------------------------------------
// LayerNorm (+g,beta) then elu+1, per row of 1024 (bf16 in/out, in-place OK).
// ---------------------------------------------------------------------------
__global__ __launch_bounds__(256) void ln_elu(
    const u16* __restrict__ X, const u16* __restrict__ g,
    const u16* __restrict__ beta, u16* __restrict__ Y)
{
  __shared__ float wsum[4], wsq[4];
  const int row = blockIdx.x, tid = threadIdx.x;
  const ushort4 xu = ((const ushort4*)(X + (size_t)row * EDIM))[tid];
  float x[4] = { b2f(xu.x), b2f(xu.y), b2f(xu.z), b2f(xu.w) };
  float s  = x[0] + x[1] + x[2] + x[3];
  float ss = x[0]*x[0] + x[1]*x[1] + x[2]*x[2] + x[3]*x[3];
#pragma unroll
  for (int off = 32; off > 0; off >>= 1) {
    s  += __shfl_down(s,  off, 64);
    ss += __shfl_down(ss, off, 64);
  }
  if ((tid & 63) == 0) { wsum[tid >> 6] = s; wsq[tid >> 6] = ss; }
  __syncthreads();
  const float S  = wsum[0] + wsum[1] + wsum[2] + wsum[3];
  const float SS = wsq[0] + wsq[1] + wsq[2] + wsq[3];
  const float mu  = S * (1.0f / EDIM);
  const float var = SS * (1.0f / EDIM) - mu * mu;
  const float rs  = rsqrtf(var + 1e-5f);
  const ushort4 gu = ((const ushort4*)g)[tid];
  const ushort4 bu = ((const ushort4*)beta)[tid];
  float gg[4] = { b2f(gu.x), b2f(gu.y), b2f(gu.z), b2f(gu.w) };
  float bb[4] = { b2f(bu.x), b2f(bu.y), b2f(bu.z), b2f(bu.w) };
  ushort4 out;
  u16 o[4];
#pragma unroll
  for (int c = 0; c < 4; ++c) {
    float y = (x[c] - mu) * rs * gg[c] + bb[c];
    y = (y > 0.f) ? (y + 1.f) : __expf(y);   // elu(y)+1
    o[c] = f2b(y);
  }
  out.x = o[0]; out.y = o[1]; out.z = o[2]; out.w = o[3];
  ((ushort4*)(Y + (size_t)row * EDIM))[tid] = out;
}

// ---------------------------------------------------------------------------
// Stage 1: per-(split,h,b) partial kv_sum (64x64 f32) + partial k_sum -> own
// global slots (NO atomics). 256 n per block, 2 chunks of 128.
// ---------------------------------------------------------------------------
__global__ __launch_bounds__(256) void kv_partial(
    const u16* __restrict__ Km, const u16* __restrict__ V,
    float* __restrict__ partials, float* __restrict__ kspart)
{
  __shared__ __align__(16) u16 smem[2 * 64 * 130];   // kT | vT, 33.3 KB
  u16 (*kT)[130] = (u16(*)[130])smem;
  u16 (*vT)[130] = (u16(*)[130])(smem + 64 * 130);
  float* red = (float*)smem;            // pitch 68; reused after MFMA (<=17.4KB)
  float* ksr = ((float*)smem) + 4352;   // 4 waves x 64 floats

  const int split = blockIdx.x, h = blockIdx.y, b = blockIdx.z;
  const int bh = b * HHEADS + h;
  const int tid = threadIdx.x, lane = tid & 63, w = tid >> 6;
  const size_t base = (size_t)b * NSEQ * EDIM + h * DHEAD;
  const int nbase = split * (NSEQ / KVSPLIT);   // 256 n per block

  float ksacc[8] = {0, 0, 0, 0, 0, 0, 0, 0};
  facc4 acc[4][4];
#pragma unroll
  for (int i = 0; i < 4; ++i)
#pragma unroll
    for (int j = 0; j < 4; ++j) acc[i][j] = (facc4){0.f, 0.f, 0.f, 0.f};

  const int e0 = (tid & 7) * 8;
  const int nl0 = tid >> 3;      // 0..31
  const int fr = lane & 15;
  const int quad = lane >> 4;

  for (int c = 0; c < 2; ++c) {
    const int nchunk = nbase + c * 128;
#pragma unroll
    for (int rep = 0; rep < 4; ++rep) {
      const int n = rep * 32 + nl0;
      const uint4 kd = *(const uint4*)(Km + base + (size_t)(nchunk + n) * EDIM + e0);
      const uint4 vd = *(const uint4*)(V  + base + (size_t)(nchunk + n) * EDIM + e0);
      const u16* pk = (const u16*)&kd;
      const u16* pv = (const u16*)&vd;
#pragma unroll
      for (int ii = 0; ii < 8; ++ii) {
        kT[e0 + ii][n] = pk[ii];
        ksacc[ii] += b2f(pk[ii]);
        vT[e0 + ii][n] = pv[ii];
      }
    }
    __syncthreads();
    const int kq2 = w * 32 + quad * 8;   // wave w contracts n in [w*32,(w+1)*32)
    frag8 af[4], bf[4];
#pragma unroll
    for (int i = 0; i < 4; ++i) af[i] = *(const frag8*)&kT[i * 16 + fr][kq2];
#pragma unroll
    for (int j = 0; j < 4; ++j) bf[j] = *(const frag8*)&vT[j * 16 + fr][kq2];
#pragma unroll
    for (int i = 0; i < 4; ++i)
#pragma unroll
      for (int j = 0; j < 4; ++j)
        acc[i][j] = __builtin_amdgcn_mfma_f32_16x16x32_bf16(af[i], bf[j], acc[i][j], 0, 0, 0);
    __syncthreads();
  }

  // rotated cross-wave reduction into red (pitch 68)
  for (int p = 0; p < 4; ++p) {
    const int j = (w + p) & 3;
#pragma unroll
    for (int i = 0; i < 4; ++i)
#pragma unroll
      for (int r = 0; r < 4; ++r) {
        const int d = i * 16 + quad * 4 + r;
        const int e = j * 16 + fr;
        if (p == 0) red[d * 68 + e] = acc[i][j][r];
        else        red[d * 68 + e] += acc[i][j][r];
      }
    __syncthreads();
  }

  // write 64x64 partial (coalesced)
  const size_t pbase = ((size_t)bh * KVSPLIT + split) * 4096;
#pragma unroll
  for (int ii = 0; ii < 16; ++ii) {
    const int idx = tid + ii * 256;
    partials[pbase + idx] = red[(idx >> 6) * 68 + (idx & 63)];
  }

  // k_sum partial: shuffle-tree over stride-8 lane groups, then cross-wave LDS
#pragma unroll
  for (int ii = 0; ii < 8; ++ii) {
    ksacc[ii] += __shfl_down(ksacc[ii], 32, 64);
    ksacc[ii] += __shfl_down(ksacc[ii], 16, 64);
    ksacc[ii] += __shfl_down(ksacc[ii], 8, 64);
  }
  if (lane < 8) {
#pragma unroll
    for (int ii = 0; ii < 8; ++ii) ksr[w * 64 + lane * 8 + ii] = ksacc[ii];
  }
  __syncthreads();
  if (tid < 64)
    kspart[((size_t)bh * KVSPLIT + split) * 64 + tid] =
        ksr[tid] + ksr[64 + tid] + ksr[128 + tid] + ksr[192 + tid];
}

// Stage 2: reduce KVSPLIT partial slots -> KV f32 [d][e] and Ks.
__global__ __launch_bounds__(256) void kv_reduce(
    const float* __restrict__ partials, const float* __restrict__ kspart,
    float* __restrict__ KV, float* __restrict__ Ks)
{
  const int qt = blockIdx.x;   // 0..3
  const int bh = blockIdx.y;   // 0..63
  const int tid = threadIdx.x;
#pragma unroll
  for (int ii = 0; ii < 4; ++ii) {
    const int idx = qt * 1024 + ii * 256 + tid;
    float s = 0.f;
#pragma unroll
    for (int sp = 0; sp < KVSPLIT; ++sp)
      s += partials[((size_t)bh * KVSPLIT + sp) * 4096 + idx];
    KV[(size_t)bh * 4096 + idx] = s;
  }
  if (qt == 0 && tid < 64) {
    float s = 0.f;
#pragma unroll
    for (int sp = 0; sp < KVSPLIT; ++sp)
      s += kspart[((size_t)bh * KVSPLIT + sp) * 64 + tid];
    Ks[bh * 64 + tid] = s;
  }
}

// ---------------------------------------------------------------------------
// attn[b,q,h,e] = (sum_d q[b,q,h,d]*kv[bh][d][e]) / (q . ksum[bh] + 1e-8)
// ---------------------------------------------------------------------------
__global__ __launch_bounds__(256) void attn_nd(
    const u16* __restrict__ Q, const float* __restrict__ KV,
    const float* __restrict__ Ks, u16* __restrict__ O)
{
  __shared__ __align__(16) u16 kvT[64][72];  // [e][d], pad +8
  __shared__ float ks_s[64];
  __shared__ float den_s[4][16];
  const int qt = blockIdx.x, h = blockIdx.y, b = blockIdx.z;
  const int bh = b * HHEADS + h;
  const int tid = threadIdx.x, lane = tid & 63, w = tid >> 6;
  const float* kvp = KV + (size_t)bh * 4096;
#pragma unroll
  for (int ii = 0; ii < 16; ++ii) {
    const int idx = tid + ii * 256;          // idx = d*64+e
    kvT[idx & 63][idx >> 6] = f2b(kvp[idx]);
  }
  if (tid < 64) ks_s[tid] = Ks[bh * 64 + tid];
  __syncthreads();

  const int fr = lane & 15;
  const int q8 = (lane >> 4) * 8;
  const u16* qp = Q + (size_t)(b * NSEQ + qt * 64 + w * 16 + fr) * EDIM + h * DHEAD;
  const frag8 a0 = *(const frag8*)(qp + q8);
  const frag8 a1 = *(const frag8*)(qp + 32 + q8);

  const u16* a0u = (const u16*)&a0;
  const u16* a1u = (const u16*)&a1;
  float den = 0.f;
#pragma unroll
  for (int j = 0; j < 8; ++j)
    den += b2f(a0u[j]) * ks_s[q8 + j] + b2f(a1u[j]) * ks_s[32 + q8 + j];
  den += __shfl_xor(den, 16, 64);
  den += __shfl_xor(den, 32, 64);
  if (lane < 16) den_s[w][lane] = den + 1e-8f;

  facc4 acc[4];
#pragma unroll
  for (int j = 0; j < 4; ++j) acc[j] = (facc4){0.f, 0.f, 0.f, 0.f};
#pragma unroll
  for (int j = 0; j < 4; ++j) {
    const frag8 b0 = *(const frag8*)&kvT[j * 16 + fr][q8];
    const frag8 b1 = *(const frag8*)&kvT[j * 16 + fr][32 + q8];
    acc[j] = __builtin_amdgcn_mfma_f32_16x16x32_bf16(a0, b0, acc[j], 0, 0, 0);
    acc[j] = __builtin_amdgcn_mfma_f32_16x16x32_bf16(a1, b1, acc[j], 0, 0, 0);
  }
  __syncthreads();
#pragma unroll
  for (int r = 0; r < 4; ++r) {
    const int rq = (lane >> 4) * 4 + r;
    const float dv = den_s[w][rq];
    const size_t orow = (size_t)(b * NSEQ + qt * 64 + w * 16 + rq) * EDIM + h * DHEAD;
#pragma unroll
    for (int j = 0; j < 4; ++j)
      O[orow + j * 16 + fr] = f2b(acc[j][r] / dv);
  }
}

// ---------------------------------------------------------------------------
extern "C" void kernel_launch(void* const* d_in, const int* in_sizes, int n_in,
                              void* d_out, int out_size, void* d_ws, size_t ws_size,
                              hipStream_t stream) {
  char* ws = (char*)d_ws;
  const size_t EH = (size_t)NTOK * EDIM;      // 16.78M elems
  unsigned* flag = (unsigned*)ws;             // 1 KB slot
  u16* Wqb  = (u16*)(ws + 1024);
  u16* Wkb  = Wqb + EDIM * EDIM;
  u16* Wvb  = Wkb + EDIM * EDIM;
  u16* Wob  = Wvb + EDIM * EDIM;
  u16* bqb  = Wob + EDIM * EDIM;
  u16* bkb  = bqb + 1024;
  u16* bvb  = bkb + 1024;
  u16* bob  = bvb + 1024;
  u16* gqb  = bob + 1024;
  u16* bEqb = gqb + 1024;
  u16* gkb  = bEqb + 1024;
  u16* bEkb = gkb + 1024;
  u16* Xin  = bEkb + 1024;    // f32-world staging; later attn output (both worlds)
  u16* preQ = Xin + EH;
  u16* preK = preQ + EH;
  u16* vbuf = preK + EH;
  float* partials = (float*)(vbuf + EH);              // 64*16*4096 f32 = 16MB
  float* kspart   = partials + (size_t)64 * KVSPLIT * 4096;  // 64*16*64 f32
  float* kvbuf    = kspart + (size_t)64 * KVSPLIT * 64;      // 64*4096 f32
  float* ksbuf    = kvbuf + (size_t)64 * 4096;               // 64*64 f32
  // total ws use ~160 MB

  const dim3 gg(256), tb(512);
  const int NW = EDIM * EDIM;

  detect_dtype<<<1, 64, 0, stream>>>((const u16*)d_in[0], flag);
  cvt_bf16<<<NW / 2048, 256, 0, stream>>>(d_in[3], Wqb, NW, flag);
  cvt_bf16<<<NW / 2048, 256, 0, stream>>>(d_in[5], Wkb, NW, flag);
  cvt_bf16<<<NW / 2048, 256, 0, stream>>>(d_in[7], Wvb, NW, flag);
  cvt_bf16<<<NW / 2048, 256, 0, stream>>>(d_in[9], Wob, NW, flag);
  Ptr8 p8;
  p8.s[0] = d_in[4];  p8.s[1] = d_in[6];  p8.s[2] = d_in[8];  p8.s[3] = d_in[10];
  p8.s[4] = d_in[11]; p8.s[5] = d_in[12]; p8.s[6] = d_in[13]; p8.s[7] = d_in[14];
  p8.d[0] = bqb; p8.d[1] = bkb; p8.d[2] = bvb; p8.d[3] = bob;
  p8.d[4] = gqb; p8.d[5] = bEqb; p8.d[6] = gkb; p8.d[7] = bEkb;
  cvt8<<<4, 256, 0, stream>>>(p8, flag);

  cvt_bf16<<<EH / 2048, 256, 0, stream>>>(d_in[0], Xin, (int)EH, flag);
  gemm256<<<gg, tb, 0, stream>>>(d_in[0], Xin, d_in[3], Wqb, bqb, preQ, flag, 0);
  cvt_bf16<<<EH / 2048, 256, 0, stream>>>(d_in[1], Xin, (int)EH, flag);
  gemm256<<<gg, tb, 0, stream>>>(d_in[1], Xin, d_in[5], Wkb, bkb, preK, flag, 0);
  cvt_bf16<<<EH / 2048, 256, 0, stream>>>(d_in[2], Xin, (int)EH, flag);
  gemm256<<<gg, tb, 0, stream>>>(d_in[2], Xin, d_in[7], Wvb, bvb, vbuf, flag, 0);

  ln_elu<<<NTOK, 256, 0, stream>>>(preQ, gqb, bEqb, preQ);   // in-place safe
  ln_elu<<<NTOK, 256, 0, stream>>>(preK, gkb, bEkb, preK);

  kv_partial<<<dim3(KVSPLIT, HHEADS, BB), dim3(256), 0, stream>>>(preK, vbuf, partials, kspart);
  kv_reduce<<<dim3(4, 64), dim3(256), 0, stream>>>(partials, kspart, kvbuf, ksbuf);
  attn_nd<<<dim3(NSEQ / 64, HHEADS, BB), dim3(256), 0, stream>>>(preQ, kvbuf, ksbuf, Xin);
  gemm256<<<gg, tb, 0, stream>>>(Xin, Xin, d_in[9], Wob, bob, (u16*)d_out, flag, 1);
}

// Round 8
// 492.596 us; speedup vs baseline: 1.1250x; 1.0522x over previous
//
#include <hip/hip_runtime.h>
#include <hip/hip_bf16.h>

// Problem constants
#define EDIM 1024
#define HHEADS 16
#define DHEAD 64
#define BB 4
#define NSEQ 4096
#define NTOK 16384   // BB*NSEQ
#define KVSPLIT 16

typedef unsigned short u16;
using frag8 = __attribute__((ext_vector_type(8))) short;   // 8 bf16 (4 VGPRs)
using facc4 = __attribute__((ext_vector_type(4))) float;   // 4 f32 acc

__device__ __forceinline__ float b2f(u16 u) {
  union { unsigned int i; float f; } c; c.i = ((unsigned int)u) << 16; return c.f;
}
__device__ __forceinline__ u16 f2b(float f) {
  __hip_bfloat16 h = __float2bfloat16(f);   // RNE
  union { __hip_bfloat16 h; u16 u; } c; c.h = h; return c.u;
}
__device__ __forceinline__ void gl2lds16(const void* g, void* l) {
  __builtin_amdgcn_global_load_lds(
      (const __attribute__((address_space(1))) unsigned int*)g,
      (__attribute__((address_space(3))) unsigned int*)l, 16, 0, 0);
}

// ---------------------------------------------------------------------------
// Dtype probe: flag[0]=1 -> inputs are bf16, 0 -> f32 (per reference).
// ---------------------------------------------------------------------------
__global__ void detect_dtype(const u16* __restrict__ src, unsigned* __restrict__ flag) {
  const int lane = threadIdx.x;                    // 64 threads
  const unsigned u = src[(size_t)lane * 200000];   // even u16 indices
  const unsigned e = (u >> 7) & 0xFF;
  const bool inl = (u == 0) || (e >= 100 && e <= 135);
  const unsigned long long m = __ballot(inl);
  if (lane == 0) flag[0] = (__popcll(m) >= 32) ? 1u : 0u;
}

// f32 -> bf16 conversion; NO-OP in bf16 world (GEMM reads raw ptr directly).
__global__ __launch_bounds__(256) void cvt_bf16(
    const void* __restrict__ src, u16* __restrict__ dst, int n,
    const unsigned* __restrict__ flag) {
  if (flag[0] == 1) return;
  const int i0 = (blockIdx.x * 256 + threadIdx.x) * 8;
  if (i0 >= n) return;
  const float4 a = ((const float4*)src)[i0 >> 2];
  const float4 b = ((const float4*)src)[(i0 >> 2) + 1];
  ushort4 lo, hi;
  lo.x = f2b(a.x); lo.y = f2b(a.y); lo.z = f2b(a.z); lo.w = f2b(a.w);
  hi.x = f2b(b.x); hi.y = f2b(b.y); hi.z = f2b(b.z); hi.w = f2b(b.w);
  ((ushort4*)dst)[i0 >> 2] = lo;
  ((ushort4*)dst)[(i0 >> 2) + 1] = hi;
}

// Two-input variant: converts in0->d0 and in1->d1 in ONE launch (R8: launch
// count reduction; d1 aliases vbuf which is dead until gemmV).
__global__ __launch_bounds__(256) void cvt_bf16_2(
    const void* __restrict__ s0, u16* __restrict__ d0,
    const void* __restrict__ s1, u16* __restrict__ d1,
    const unsigned* __restrict__ flag) {
  if (flag[0] == 1) return;
  const void* s = blockIdx.y ? s1 : s0;
  u16* d = blockIdx.y ? d1 : d0;
  const int i0 = (blockIdx.x * 256 + threadIdx.x) * 8;
  const float4 a = ((const float4*)s)[i0 >> 2];
  const float4 b = ((const float4*)s)[(i0 >> 2) + 1];
  ushort4 lo, hi;
  lo.x = f2b(a.x); lo.y = f2b(a.y); lo.z = f2b(a.z); lo.w = f2b(a.w);
  hi.x = f2b(b.x); hi.y = f2b(b.y); hi.z = f2b(b.z); hi.w = f2b(b.w);
  ((ushort4*)d)[i0 >> 2] = lo;
  ((ushort4*)d)[(i0 >> 2) + 1] = hi;
}

// Merged weight/vector conversion: blocks [0,2048) convert the 4 weight
// matrices (512 blocks each); blocks [2048,2052) convert the 8 small vectors.
// One launch replaces 5 (R8).
struct Ptr8 { const void* s[8]; u16* d[8]; };
struct WcvtArgs { const void* ws[4]; u16* wd[4]; Ptr8 p8; };
__global__ __launch_bounds__(256) void wcvt_all(WcvtArgs a, const unsigned* __restrict__ flag) {
  const int blk = blockIdx.x;
  if (blk < 2048) {
    if (flag[0] == 1) return;
    const int v = blk >> 9;
    const int i0 = (((blk & 511) * 256) + threadIdx.x) * 8;
    const void* s = a.ws[v];
    u16* d = a.wd[v];
    const float4 x = ((const float4*)s)[i0 >> 2];
    const float4 y = ((const float4*)s)[(i0 >> 2) + 1];
    ushort4 lo, hi;
    lo.x = f2b(x.x); lo.y = f2b(x.y); lo.z = f2b(x.z); lo.w = f2b(x.w);
    hi.x = f2b(y.x); hi.y = f2b(y.y); hi.z = f2b(y.z); hi.w = f2b(y.w);
    ((ushort4*)d)[i0 >> 2] = lo;
    ((ushort4*)d)[(i0 >> 2) + 1] = hi;
  } else {
    const int t = (blk - 2048) * 256 + threadIdx.x;   // 0..1023
    const int v = t >> 7;
    const int i0 = (t & 127) * 8;
    const void* s = a.p8.s[v];
    u16* d = a.p8.d[v];
    ushort4 lo, hi;
    if (flag[0] == 0) {
      const float4 x = ((const float4*)s)[i0 >> 2];
      const float4 y = ((const float4*)s)[(i0 >> 2) + 1];
      lo.x = f2b(x.x); lo.y = f2b(x.y); lo.z = f2b(x.z); lo.w = f2b(x.w);
      hi.x = f2b(y.x); hi.y = f2b(y.y); hi.z = f2b(y.z); hi.w = f2b(y.w);
    } else {
      lo = ((const ushort4*)s)[i0 >> 2];
      hi = ((const ushort4*)s)[(i0 >> 2) + 1];
    }
    ((ushort4*)d)[i0 >> 2] = lo;
    ((ushort4*)d)[(i0 >> 2) + 1] = hi;
  }
}

// ---------------------------------------------------------------------------
// GEMM: identical to R7 (harness-verified). 256x256 tile, BK=64, 8 waves,
// 4-phase counted-vmcnt schedule with A-per-phase + B-reg-cached reads.
// ---------------------------------------------------------------------------
#define STA(BUF, QM, T)                                                       \
  gl2lds16(Ag + (size_t)(QM) * 64 * EDIM + (size_t)(T) * 64,                  \
           AsW + (BUF) * 16384 + (QM) * 8192);                                \
  gl2lds16(Ag + (size_t)(QM) * 64 * EDIM + 128 * EDIM + (size_t)(T) * 64,     \
           AsW + (BUF) * 16384 + (QM) * 8192 + 4096);

#define STB(BUF, QN, T)                                                       \
  gl2lds16(Bg + (size_t)(QN) * 32 * EDIM + (size_t)(T) * 64,                  \
           BsW + (BUF) * 16384 + (QN) * 8192);                                \
  gl2lds16(Bg + (size_t)(QN) * 32 * EDIM + 128 * EDIM + (size_t)(T) * 64,     \
           BsW + (BUF) * 16384 + (QN) * 8192 + 4096);

#define VM(N) asm volatile("s_waitcnt vmcnt(" #N ")" ::: "memory");

#define PH4(BUF, QM, LOADB, ISSUE, TAIL)                                      \
  {                                                                           \
    _Pragma("unroll") for (int i = 0; i < 4; ++i) {                           \
      const u16* rp = &As[BUF][QM][wm * 64 + i * 16 + fr][0];                 \
      af[i][0] = *(const frag8*)(rp + c0);                                    \
      af[i][1] = *(const frag8*)(rp + c1);                                    \
    }                                                                         \
    if (LOADB) {                                                              \
      _Pragma("unroll") for (int j = 0; j < 4; ++j) {                         \
        const u16* rp = &Bs[BUF][j >> 1][wn * 32 + (j & 1) * 16 + fr][0];     \
        bq[j][0] = *(const frag8*)(rp + c0);                                  \
        bq[j][1] = *(const frag8*)(rp + c1);                                  \
      }                                                                       \
    }                                                                         \
    ISSUE                                                                     \
    __builtin_amdgcn_s_barrier();                                             \
    asm volatile("s_waitcnt lgkmcnt(0)" ::: "memory");                        \
    __builtin_amdgcn_sched_barrier(0);                                        \
    __builtin_amdgcn_s_setprio(1);                                            \
    _Pragma("unroll") for (int kk = 0; kk < 2; ++kk)                          \
      _Pragma("unroll") for (int i = 0; i < 4; ++i)                           \
        _Pragma("unroll") for (int j = 0; j < 4; ++j)                         \
          acc[(QM) * 4 + i][j] =                                              \
              __builtin_amdgcn_mfma_f32_16x16x32_bf16(                        \
                  af[i][kk], bq[j][kk], acc[(QM) * 4 + i][j], 0, 0, 0);       \
    __builtin_amdgcn_s_setprio(0);                                            \
    TAIL                                                                      \
    __builtin_amdgcn_s_barrier();                                             \
    __builtin_amdgcn_sched_barrier(0);                                        \
  }

__global__ __launch_bounds__(512, 2) void gemm256(
    const void* __restrict__ Araw, const u16* __restrict__ Acvt,
    const void* __restrict__ Wraw, const u16* __restrict__ Wcvt,
    const u16* __restrict__ bias, u16* __restrict__ C,
    const unsigned* __restrict__ flag, int outMode)
{
  __shared__ __align__(16) u16 As[2][2][128][64];   // 64 KiB
  __shared__ __align__(16) u16 Bs[2][2][128][64];   // 64 KiB

  const int tid  = threadIdx.x;
  const int lane = tid & 63;
  const int w    = tid >> 6;       // 0..7
  const int wm   = w >> 2;         // 0..1 (M half)
  const int wn   = w & 3;          // 0..3 (N quarter)

  const int bid0 = blockIdx.x;
  const int bid  = (bid0 & 7) * 32 + (bid0 >> 3);
  const int rowBase = (bid >> 2) * 256;
  const int colBase = (bid & 3) * 256;

  const bool bfw = (flag[0] == 1);
  const u16* A  = bfw ? (const u16*)Araw : Acvt;
  const u16* Wt = bfw ? (const u16*)Wraw : Wcvt;

  const int lr = w * 8 + (lane >> 3);               // row within 64-row op
  const int sc = 8 * ((lane & 7) ^ (lane >> 3));    // swizzled col (elems)
  const u16* Ag = A  + (size_t)(rowBase + lr) * EDIM + sc;
  const u16* Bg = Wt + (size_t)(colBase + (lr >> 5) * 64 + (lr & 31)) * EDIM + sc;
  u16* AsW = &As[0][0][w * 8][0];   // + buf*16384 + region*8192 + o*4096
  u16* BsW = &Bs[0][0][w * 8][0];

  const int fr = lane & 15;
  const int qd = lane >> 4;
  const int sw = fr & 7;
  const int c0 = 8 * (qd ^ sw);          // kk=0 swizzled col offset (elems)
  const int c1 = 8 * ((qd + 4) ^ sw);    // kk=1

  facc4 acc[8][4];
#pragma unroll
  for (int i = 0; i < 8; ++i)
#pragma unroll
    for (int j = 0; j < 4; ++j) acc[i][j] = (facc4){0.f, 0.f, 0.f, 0.f};

  frag8 af[4][2];
  frag8 bq[4][2];

  STA(0, 0, 0) STB(0, 0, 0) STA(0, 1, 0) STB(0, 1, 0)
  STA(1, 0, 1) STB(1, 0, 1)
  VM(4)
  __builtin_amdgcn_s_barrier();
  __builtin_amdgcn_sched_barrier(0);

#pragma unroll 1
  for (int it = 0; it < 7; ++it) {                  // tiles 0..13
    const int t1 = 2 * it + 1, t2 = t1 + 1, t3 = t1 + 2;
    PH4(0, 0, 1, STA(1, 1, t1) STB(1, 1, t1), )
    PH4(0, 1, 0, STA(0, 0, t2) STB(0, 0, t2), VM(4))
    PH4(1, 0, 1, STA(0, 1, t2) STB(0, 1, t2), )
    PH4(1, 1, 0, STA(1, 0, t3) STB(1, 0, t3), VM(4))
  }
  PH4(0, 0, 1, STA(1, 1, 15) STB(1, 1, 15), )
  PH4(0, 1, 0, , VM(0))
  PH4(1, 0, 1, , )
  PH4(1, 1, 0, , )

  const bool f32out = (outMode == 1) && !bfw;
  float* Cf = (float*)C;
  float bvv[4];
#pragma unroll
  for (int j = 0; j < 4; ++j)
    bvv[j] = b2f(bias[colBase + wn * 64 + j * 16 + fr]);
#pragma unroll
  for (int i = 0; i < 8; ++i) {
#pragma unroll
    for (int r = 0; r < 4; ++r) {
      const int row = rowBase + wm * 128 + i * 16 + qd * 4 + r;
      const size_t ro = (size_t)row * EDIM + colBase + wn * 64 + fr;
#pragma unroll
      for (int j = 0; j < 4; ++j) {
        const float val = acc[i][j][r] + bvv[j];
        if (f32out) Cf[ro + j * 16] = val;
        else        C[ro + j * 16]  = f2b(val);
      }
    }
  }
}

// ---------------------------------------------------------------------------
// R8 LayerNorm+elu+1: BOTH tensors in one launch; one wave per row (16
// elems/lane), pure-shuffle reduction — no LDS, no __syncthreads.
// Grid: 8192 blocks x 256 threads = 32768 waves = 2*NTOK rows.
// ---------------------------------------------------------------------------
struct LnArgs {
  const u16* X0; const u16* g0; const u16* b0; u16* Y0;
  const u16* X1; const u16* g1; const u16* b1; u16* Y1;
};
__global__ __launch_bounds__(256) void ln_elu2(LnArgs a) {
  const int tid = threadIdx.x, wv = tid >> 6, lane = tid & 63;
  const int rowg = blockIdx.x * 4 + wv;            // 0..32767
  const int sel = rowg >= NTOK;                    // wave-uniform
  const int row = sel ? rowg - NTOK : rowg;
  const u16* X = sel ? a.X1 : a.X0;
  const u16* g = sel ? a.g1 : a.g0;
  const u16* be = sel ? a.b1 : a.b0;
  u16* Y = sel ? a.Y1 : a.Y0;

  const uint4* xr = (const uint4*)(X + (size_t)row * EDIM);
  const uint4 v0 = xr[lane * 2];
  const uint4 v1 = xr[lane * 2 + 1];
  float xv[16];
  const u16* p0 = (const u16*)&v0;
  const u16* p1 = (const u16*)&v1;
#pragma unroll
  for (int j = 0; j < 8; ++j) { xv[j] = b2f(p0[j]); xv[8 + j] = b2f(p1[j]); }
  float s = 0.f, ss = 0.f;
#pragma unroll
  for (int j = 0; j < 16; ++j) { s += xv[j]; ss += xv[j] * xv[j]; }
#pragma unroll
  for (int off = 1; off < 64; off <<= 1) {
    s  += __shfl_xor(s,  off, 64);
    ss += __shfl_xor(ss, off, 64);
  }
  const float mu  = s * (1.0f / EDIM);
  const float var = ss * (1.0f / EDIM) - mu * mu;
  const float rs  = rsqrtf(var + 1e-5f);

  const uint4 gu0 = ((const uint4*)g)[lane * 2];
  const uint4 gu1 = ((const uint4*)g)[lane * 2 + 1];
  const uint4 bu0 = ((const uint4*)be)[lane * 2];
  const uint4 bu1 = ((const uint4*)be)[lane * 2 + 1];
  const u16* pg0 = (const u16*)&gu0; const u16* pg1 = (const u16*)&gu1;
  const u16* pb0 = (const u16*)&bu0; const u16* pb1 = (const u16*)&bu1;
  u16 o[16];
#pragma unroll
  for (int j = 0; j < 16; ++j) {
    const float gg = b2f(j < 8 ? pg0[j] : pg1[j - 8]);
    const float bb = b2f(j < 8 ? pb0[j] : pb1[j - 8]);
    float y = (xv[j] - mu) * rs * gg + bb;
    y = (y > 0.f) ? (y + 1.f) : __expf(y);   // elu(y)+1
    o[j] = f2b(y);
  }
  uint4* yr = (uint4*)(Y + (size_t)row * EDIM);
  yr[lane * 2]     = *(const uint4*)&o[0];
  yr[lane * 2 + 1] = *(const uint4*)&o[8];
}

// ---------------------------------------------------------------------------
// Stage 1: per-(split,h,b) partial kv_sum (64x64 f32) + partial k_sum -> own
// global slots (NO atomics). 256 n per block, 2 chunks of 128.  (unchanged)
// ---------------------------------------------------------------------------
__global__ __launch_bounds__(256) void kv_partial(
    const u16* __restrict__ Km, const u16* __restrict__ V,
    float* __restrict__ partials, float* __restrict__ kspart)
{
  __shared__ __align__(16) u16 smem[2 * 64 * 130];   // kT | vT, 33.3 KB
  u16 (*kT)[130] = (u16(*)[130])smem;
  u16 (*vT)[130] = (u16(*)[130])(smem + 64 * 130);
  float* red = (float*)smem;            // pitch 68; reused after MFMA (<=17.4KB)
  float* ksr = ((float*)smem) + 4352;   // 4 waves x 64 floats

  const int split = blockIdx.x, h = blockIdx.y, b = blockIdx.z;
  const int bh = b * HHEADS + h;
  const int tid = threadIdx.x, lane = tid & 63, w = tid >> 6;
  const size_t base = (size_t)b * NSEQ * EDIM + h * DHEAD;
  const int nbase = split * (NSEQ / KVSPLIT);   // 256 n per block

  float ksacc[8] = {0, 0, 0, 0, 0, 0, 0, 0};
  facc4 acc[4][4];
#pragma unroll
  for (int i = 0; i < 4; ++i)
#pragma unroll
    for (int j = 0; j < 4; ++j) acc[i][j] = (facc4){0.f, 0.f, 0.f, 0.f};

  const int e0 = (tid & 7) * 8;
  const int nl0 = tid >> 3;      // 0..31
  const int fr = lane & 15;
  const int quad = lane >> 4;

  for (int c = 0; c < 2; ++c) {
    const int nchunk = nbase + c * 128;
#pragma unroll
    for (int rep = 0; rep < 4; ++rep) {
      const int n = rep * 32 + nl0;
      const uint4 kd = *(const uint4*)(Km + base + (size_t)(nchunk + n) * EDIM + e0);
      const uint4 vd = *(const uint4*)(V  + base + (size_t)(nchunk + n) * EDIM + e0);
      const u16* pk = (const u16*)&kd;
      const u16* pv = (const u16*)&vd;
#pragma unroll
      for (int ii = 0; ii < 8; ++ii) {
        kT[e0 + ii][n] = pk[ii];
        ksacc[ii] += b2f(pk[ii]);
        vT[e0 + ii][n] = pv[ii];
      }
    }
    __syncthreads();
    const int kq2 = w * 32 + quad * 8;   // wave w contracts n in [w*32,(w+1)*32)
    frag8 af[4], bf[4];
#pragma unroll
    for (int i = 0; i < 4; ++i) af[i] = *(const frag8*)&kT[i * 16 + fr][kq2];
#pragma unroll
    for (int j = 0; j < 4; ++j) bf[j] = *(const frag8*)&vT[j * 16 + fr][kq2];
#pragma unroll
    for (int i = 0; i < 4; ++i)
#pragma unroll
      for (int j = 0; j < 4; ++j)
        acc[i][j] = __builtin_amdgcn_mfma_f32_16x16x32_bf16(af[i], bf[j], acc[i][j], 0, 0, 0);
    __syncthreads();
  }

  // rotated cross-wave reduction into red (pitch 68)
  for (int p = 0; p < 4; ++p) {
    const int j = (w + p) & 3;
#pragma unroll
    for (int i = 0; i < 4; ++i)
#pragma unroll
      for (int r = 0; r < 4; ++r) {
        const int d = i * 16 + quad * 4 + r;
        const int e = j * 16 + fr;
        if (p == 0) red[d * 68 + e] = acc[i][j][r];
        else        red[d * 68 + e] += acc[i][j][r];
      }
    __syncthreads();
  }

  // write 64x64 partial (coalesced)
  const size_t pbase = ((size_t)bh * KVSPLIT + split) * 4096;
#pragma unroll
  for (int ii = 0; ii < 16; ++ii) {
    const int idx = tid + ii * 256;
    partials[pbase + idx] = red[(idx >> 6) * 68 + (idx & 63)];
  }

  // k_sum partial: shuffle-tree over stride-8 lane groups, then cross-wave LDS
#pragma unroll
  for (int ii = 0; ii < 8; ++ii) {
    ksacc[ii] += __shfl_down(ksacc[ii], 32, 64);
    ksacc[ii] += __shfl_down(ksacc[ii], 16, 64);
    ksacc[ii] += __shfl_down(ksacc[ii], 8, 64);
  }
  if (lane < 8) {
#pragma unroll
    for (int ii = 0; ii < 8; ++ii) ksr[w * 64 + lane * 8 + ii] = ksacc[ii];
  }
  __syncthreads();
  if (tid < 64)
    kspart[((size_t)bh * KVSPLIT + split) * 64 + tid] =
        ksr[tid] + ksr[64 + tid] + ksr[128 + tid] + ksr[192 + tid];
}

// Stage 2: reduce KVSPLIT partial slots -> KV bf16 [d][e] (R8) and Ks f32.
__global__ __launch_bounds__(256) void kv_reduce(
    const float* __restrict__ partials, const float* __restrict__ kspart,
    u16* __restrict__ KVb, float* __restrict__ Ks)
{
  const int qt = blockIdx.x;   // 0..3
  const int bh = blockIdx.y;   // 0..63
  const int tid = threadIdx.x;
#pragma unroll
  for (int ii = 0; ii < 4; ++ii) {
    const int idx = qt * 1024 + ii * 256 + tid;
    float s = 0.f;
#pragma unroll
    for (int sp = 0; sp < KVSPLIT; ++sp)
      s += partials[((size_t)bh * KVSPLIT + sp) * 4096 + idx];
    KVb[(size_t)bh * 4096 + idx] = f2b(s);
  }
  if (qt == 0 && tid < 64) {
    float s = 0.f;
#pragma unroll
    for (int sp = 0; sp < KVSPLIT; ++sp)
      s += kspart[((size_t)bh * KVSPLIT + sp) * 64 + tid];
    Ks[bh * 64 + tid] = s;
  }
}

// ---------------------------------------------------------------------------
// attn[b,q,h,e] = (sum_d q[b,q,h,d]*kv[bh][d][e]) / (q . ksum[bh] + 1e-8)
// R8: KV arrives pre-converted bf16 (half the bytes, no per-block f2b).
// ---------------------------------------------------------------------------
__global__ __launch_bounds__(256) void attn_nd(
    const u16* __restrict__ Q, const u16* __restrict__ KVb,
    const float* __restrict__ Ks, u16* __restrict__ O)
{
  __shared__ __align__(16) u16 kvT[64][72];  // [e][d], pad +8
  __shared__ float ks_s[64];
  __shared__ float den_s[4][16];
  const int qt = blockIdx.x, h = blockIdx.y, b = blockIdx.z;
  const int bh = b * HHEADS + h;
  const int tid = threadIdx.x, lane = tid & 63, w = tid >> 6;
  const u16* kvp = KVb + (size_t)bh * 4096;
#pragma unroll
  for (int ii = 0; ii < 16; ++ii) {
    const int idx = tid + ii * 256;          // idx = d*64+e
    kvT[idx & 63][idx >> 6] = kvp[idx];
  }
  if (tid < 64) ks_s[tid] = Ks[bh * 64 + tid];
  __syncthreads();

  const int fr = lane & 15;
  const int q8 = (lane >> 4) * 8;
  const u16* qp = Q + (size_t)(b * NSEQ + qt * 64 + w * 16 + fr) * EDIM + h * DHEAD;
  const frag8 a0 = *(const frag8*)(qp + q8);
  const frag8 a1 = *(const frag8*)(qp + 32 + q8);

  const u16* a0u = (const u16*)&a0;
  const u16* a1u = (const u16*)&a1;
  float den = 0.f;
#pragma unroll
  for (int j = 0; j < 8; ++j)
    den += b2f(a0u[j]) * ks_s[q8 + j] + b2f(a1u[j]) * ks_s[32 + q8 + j];
  den += __shfl_xor(den, 16, 64);
  den += __shfl_xor(den, 32, 64);
  if (lane < 16) den_s[w][lane] = den + 1e-8f;

  facc4 acc[4];
#pragma unroll
  for (int j = 0; j < 4; ++j) acc[j] = (facc4){0.f, 0.f, 0.f, 0.f};
#pragma unroll
  for (int j = 0; j < 4; ++j) {
    const frag8 b0 = *(const frag8*)&kvT[j * 16 + fr][q8];
    const frag8 b1 = *(const frag8*)&kvT[j * 16 + fr][32 + q8];
    acc[j] = __builtin_amdgcn_mfma_f32_16x16x32_bf16(a0, b0, acc[j], 0, 0, 0);
    acc[j] = __builtin_amdgcn_mfma_f32_16x16x32_bf16(a1, b1, acc[j], 0, 0, 0);
  }
  __syncthreads();
#pragma unroll
  for (int r = 0; r < 4; ++r) {
    const int rq = (lane >> 4) * 4 + r;
    const float dv = den_s[w][rq];
    const size_t orow = (size_t)(b * NSEQ + qt * 64 + w * 16 + rq) * EDIM + h * DHEAD;
#pragma unroll
    for (int j = 0; j < 4; ++j)
      O[orow + j * 16 + fr] = f2b(acc[j][r] / dv);
  }
}

// ---------------------------------------------------------------------------
extern "C" void kernel_launch(void* const* d_in, const int* in_sizes, int n_in,
                              void* d_out, int out_size, void* d_ws, size_t ws_size,
                              hipStream_t stream) {
  char* ws = (char*)d_ws;
  const size_t EH = (size_t)NTOK * EDIM;      // 16.78M elems
  unsigned* flag = (unsigned*)ws;             // 1 KB slot
  u16* Wqb  = (u16*)(ws + 1024);
  u16* Wkb  = Wqb + EDIM * EDIM;
  u16* Wvb  = Wkb + EDIM * EDIM;
  u16* Wob  = Wvb + EDIM * EDIM;
  u16* bqb  = Wob + EDIM * EDIM;
  u16* bkb  = bqb + 1024;
  u16* bvb  = bkb + 1024;
  u16* bob  = bvb + 1024;
  u16* gqb  = bob + 1024;
  u16* bEqb = gqb + 1024;
  u16* gkb  = bEqb + 1024;
  u16* bEkb = gkb + 1024;
  u16* Xin  = bEkb + 1024;    // staging A; later attn output
  u16* preQ = Xin + EH;
  u16* preK = preQ + EH;
  u16* vbuf = preK + EH;      // staging B for K-embed (dead until gemmV), then V
  float* partials = (float*)(vbuf + EH);              // 64*16*4096 f32 = 16MB
  float* kspart   = partials + (size_t)64 * KVSPLIT * 4096;  // 64*16*64 f32
  float* kvbuf    = kspart + (size_t)64 * KVSPLIT * 64;      // 64*4096 f32 slot
  float* ksbuf    = kvbuf + (size_t)64 * 4096;               // 64*64 f32
  u16* kvbf = (u16*)kvbuf;    // bf16 KV lives in the old f32 slot (R8)

  const dim3 gg(256), tb(512);

  detect_dtype<<<1, 64, 0, stream>>>((const u16*)d_in[0], flag);

  WcvtArgs wa;
  wa.ws[0] = d_in[3]; wa.ws[1] = d_in[5]; wa.ws[2] = d_in[7]; wa.ws[3] = d_in[9];
  wa.wd[0] = Wqb;     wa.wd[1] = Wkb;     wa.wd[2] = Wvb;     wa.wd[3] = Wob;
  wa.p8.s[0] = d_in[4];  wa.p8.s[1] = d_in[6];  wa.p8.s[2] = d_in[8];  wa.p8.s[3] = d_in[10];
  wa.p8.s[4] = d_in[11]; wa.p8.s[5] = d_in[12]; wa.p8.s[6] = d_in[13]; wa.p8.s[7] = d_in[14];
  wa.p8.d[0] = bqb; wa.p8.d[1] = bkb; wa.p8.d[2] = bvb; wa.p8.d[3] = bob;
  wa.p8.d[4] = gqb; wa.p8.d[5] = bEqb; wa.p8.d[6] = gkb; wa.p8.d[7] = bEkb;
  wcvt_all<<<2052, 256, 0, stream>>>(wa, flag);

  cvt_bf16_2<<<dim3(EH / 2048, 2), 256, 0, stream>>>(d_in[0], Xin, d_in[1], vbuf, flag);
  gemm256<<<gg, tb, 0, stream>>>(d_in[0], Xin,  d_in[3], Wqb, bqb, preQ, flag, 0);
  gemm256<<<gg, tb, 0, stream>>>(d_in[1], vbuf, d_in[5], Wkb, bkb, preK, flag, 0);
  cvt_bf16<<<EH / 2048, 256, 0, stream>>>(d_in[2], Xin, (int)EH, flag);
  gemm256<<<gg, tb, 0, stream>>>(d_in[2], Xin,  d_in[7], Wvb, bvb, vbuf, flag, 0);

  LnArgs la;
  la.X0 = preQ; la.g0 = gqb; la.b0 = bEqb; la.Y0 = preQ;
  la.X1 = preK; la.g1 = gkb; la.b1 = bEkb; la.Y1 = preK;
  ln_elu2<<<8192, 256, 0, stream>>>(la);

  kv_partial<<<dim3(KVSPLIT, HHEADS, BB), dim3(256), 0, stream>>>(preK, vbuf, partials, kspart);
  kv_reduce<<<dim3(4, 64), dim3(256), 0, stream>>>(partials, kspart, kvbf, ksbuf);
  attn_nd<<<dim3(NSEQ / 64, HHEADS, BB), dim3(256), 0, stream>>>(preQ, kvbf, ksbuf, Xin);
  gemm256<<<gg, tb, 0, stream>>>(Xin, Xin, d_in[9], Wob, bob, (u16*)d_out, flag, 1);
}